// Round 15
// baseline (124.730 us; speedup 1.0000x reference)
//
#include <hip/hip_runtime.h>
#include <cstdint>
#include <cstddef>

// ---------------- problem constants ----------------
#define BB 4
#define SS 2048
#define EE 512
#define HH 8
#define DD 64
#define MM (BB*SS)                       // 8192 token rows
#define BHSD ((size_t)BB*HH*SS*DD)       // 4194304 elements per q/k/v head tensor

static constexpr float SCALE_INV = 1.0f / 181.0f;   // SCALE = float(512 // 8**0.5) = 181.0
static constexpr float LOG2E = 1.4426950408889634f;
static constexpr float LN_EPS = 1e-5f;

typedef float  v4f  __attribute__((ext_vector_type(4)));
typedef __bf16 v8bf __attribute__((ext_vector_type(8)));
typedef __bf16 v4bf __attribute__((ext_vector_type(4)));
typedef short  s4   __attribute__((ext_vector_type(4)));

static __device__ __forceinline__ v4f mfma16(v8bf a, v8bf b, v4f c) {
  return __builtin_amdgcn_mfma_f32_16x16x32_bf16(a, b, c, 0, 0, 0);
}

// async global->LDS, 16B per lane; LDS dest = wave-uniform base + lane*16 (HW rule).
typedef const void __attribute__((address_space(1))) gas_void;
typedef void __attribute__((address_space(3))) las_void;
static __device__ __forceinline__ void gload_lds16(const void* g, void* l) {
  __builtin_amdgcn_global_load_lds((gas_void*)g, (las_void*)l, 16, 0, 0);
}

// ---------------- workspace layout (bytes) ----------------
static constexpr size_t oXb = 0;
static constexpr size_t oWb = oXb + (size_t)3*MM*EE*2;
static constexpr size_t oXh = oWb + (size_t)4*EE*EE*2;
static constexpr size_t oAO = oXh + (size_t)3*MM*EE*2;
static constexpr size_t oMk = oAO + (size_t)MM*EE*2;

// ================= mask canonicalization (parallel) =================
__global__ void mask_kernel(const void* qm, const void* km, const void* vm, float* maskF) {
  __shared__ int s_n01, s_nF;
  const int t = threadIdx.x;
  if (t == 0) { s_n01 = 0; s_nF = 0; }
  __syncthreads();
  int n01 = 0, nF = 0;
  const unsigned* wq = (const unsigned*)qm;
  for (int i = t; i < 2048; i += 256) {
    const unsigned u = wq[i];
    if (u != 0u && u != 1u) n01 = 1;
    if (u != 0u && u != 0x3F800000u) nF = 1;
  }
  if (n01) atomicOr(&s_n01, 1);
  if (nF)  atomicOr(&s_nF, 1);
  __syncthreads();
  const int mode = (!s_n01) ? 0 : (!s_nF) ? 1 : 2;   // 0=i32, 1=f32, 2=u8
  const int gidx = blockIdx.x * 256 + t;
  const int m = gidx / MM, i = gidx % MM;
  const void* p = (m == 0) ? qm : (m == 1) ? km : vm;
  int v;
  if (mode == 0)      v = (((const int*)p)[i] != 0);
  else if (mode == 1) v = (((const unsigned*)p)[i] != 0u);
  else                v = (((const unsigned char*)p)[i] != 0);
  maskF[m*MM + i] = v ? 1.0f : 0.0f;
}

// ================= fp32 -> bf16 convert =================
__global__ void convert_kernel(const float* q, const float* k, const float* v,
                               const float* Wq, const float* Wk, const float* Wv, const float* Wo,
                               __bf16* Xb, __bf16* Wb) {
  const long idx = (long)blockIdx.x * 256 + threadIdx.x;     // in float4 units
  const long NX4 = (long)3*MM*EE/4;
  const long NW4 = (long)4*EE*EE/4;
  if (idx < NX4) {
    const long per = (long)MM*EE/4;
    const long mat = idx / per, off = idx % per;
    const float* src = (mat == 0) ? q : (mat == 1) ? k : v;
    v4f val = ((const v4f*)src)[off];
    v4bf o; o[0]=(__bf16)val[0]; o[1]=(__bf16)val[1]; o[2]=(__bf16)val[2]; o[3]=(__bf16)val[3];
    ((v4bf*)Xb)[idx] = o;
  } else if (idx < NX4 + NW4) {
    const long j = idx - NX4;
    const long per = (long)EE*EE/4;
    const long mat = j / per, off = j % per;
    const float* src = (mat == 0) ? Wq : (mat == 1) ? Wk : (mat == 2) ? Wv : Wo;
    v4f val = ((const v4f*)src)[off];
    v4bf o; o[0]=(__bf16)val[0]; o[1]=(__bf16)val[1]; o[2]=(__bf16)val[2]; o[3]=(__bf16)val[3];
    ((v4bf*)Wb)[j] = o;
  }
}

// ===== projection GEMM + bias + mask + per-head LayerNorm, fused =====
// (unchanged from round 11 -- m97-style 2-phase, passing)
__global__ __launch_bounds__(256) void gemm_proj_ln(const __bf16* Xb, const __bf16* Wb,
                                                    const float* bq, const float* bk, const float* bv,
                                                    const float* gq, const float* betaq,
                                                    const float* gk, const float* betak,
                                                    const float* gv, const float* betav,
                                                    const float* maskF, __bf16* Xh) {
  const int m0  = blockIdx.x * 128;
  const int n0  = blockIdx.y * 128;
  const int mat = blockIdx.z;
  const __bf16* A = Xb + (size_t)mat*MM*EE;
  const __bf16* W = Wb + (size_t)mat*EE*EE;
  const float* bias = (mat == 0) ? bq : (mat == 1) ? bk : bv;
  const float* gam  = (mat == 0) ? gq : (mat == 1) ? gk : gv;
  const float* bet  = (mat == 0) ? betaq : (mat == 1) ? betak : betav;

  __shared__ char smem[32768];   // [buf][A 8KB | B 8KB]

  const int t = threadIdx.x;
  const int lane = t & 63, w = t >> 6;
  const int wm = w >> 1, wn = w & 1;
  const int l15 = lane & 15, lg = lane >> 4;

  v4f acc[4][4];
  const v4f zf = {0.f, 0.f, 0.f, 0.f};
#pragma unroll
  for (int i = 0; i < 4; ++i)
#pragma unroll
    for (int j = 0; j < 4; ++j) acc[i][j] = zf;

  const int sr0 = (w*64 + lane) >> 2;
  const int sct = (w*64 + lane) & 3;
#define STAGE_PL(BUF, KT)                                                                 \
  {                                                                                       \
    char* ab_ = (BUF);                                                                    \
    char* bb_ = (BUF) + 8192;                                                             \
    _Pragma("unroll")                                                                     \
    for (int j_ = 0; j_ < 2; ++j_) {                                                      \
      const int r_ = sr0 + j_*64;                                                         \
      const int c_ = sct ^ (r_ & 3);                                                      \
      gload_lds16(A + (size_t)(m0 + r_)*EE + (KT) + c_*8, ab_ + j_*4096 + w*1024);        \
      gload_lds16(W + (size_t)(n0 + r_)*EE + (KT) + c_*8, bb_ + j_*4096 + w*1024);        \
    }                                                                                     \
  }

  char* buf0 = smem;
  char* buf1 = smem + 16384;

  STAGE_PL(buf0, 0);
  __syncthreads();

  int cur = 0;
  for (int kt = 0; kt < EE; kt += 32) {
    char* cb = cur ? buf1 : buf0;
    char* nb = cur ? buf0 : buf1;
    if (kt + 32 < EE) STAGE_PL(nb, kt + 32);

    const char* As = cb;
    const char* Bs = cb + 8192;
    v8bf afr[4], bfr[4];
#pragma unroll
    for (int i = 0; i < 4; ++i) {
      const int ra = wm*64 + i*16 + l15;
      afr[i] = *(const v8bf*)(As + ra*64 + ((16*lg) ^ ((ra & 3) << 4)));
      const int rb = wn*64 + i*16 + l15;
      bfr[i] = *(const v8bf*)(Bs + rb*64 + ((16*lg) ^ ((rb & 3) << 4)));
    }
#pragma unroll
    for (int i = 0; i < 4; ++i)
#pragma unroll
      for (int j = 0; j < 4; ++j)
        acc[i][j] = mfma16(afr[i], bfr[j], acc[i][j]);
    __syncthreads();
    cur ^= 1;
  }
#undef STAGE_PL

  const int nbase = n0 + wn*64;          // 64-aligned => one head
  const int h = nbase >> 6;
  float bsv[4], gmv[4], btv[4];
#pragma unroll
  for (int j = 0; j < 4; ++j) {
    const int d = j*16 + l15;
    bsv[j] = bias[nbase + d];
    gmv[j] = gam[d];
    btv[j] = bet[d];
  }
#pragma unroll
  for (int i = 0; i < 4; ++i)
#pragma unroll
    for (int rr = 0; rr < 4; ++rr) {
      const int row = m0 + wm*64 + i*16 + 4*lg + rr;
      const float mv = maskF[mat*MM + row];
      float x[4];
      float s = 0.f, s2 = 0.f;
#pragma unroll
      for (int j = 0; j < 4; ++j) {
        x[j] = (acc[i][j][rr] + bsv[j]) * mv;
        s += x[j]; s2 += x[j]*x[j];
      }
      s  += __shfl_xor(s, 1, 64);  s  += __shfl_xor(s, 2, 64);
      s  += __shfl_xor(s, 4, 64);  s  += __shfl_xor(s, 8, 64);
      s2 += __shfl_xor(s2, 1, 64); s2 += __shfl_xor(s2, 2, 64);
      s2 += __shfl_xor(s2, 4, 64); s2 += __shfl_xor(s2, 8, 64);
      const float mu  = s * (1.0f/64.0f);
      const float var = s2 * (1.0f/64.0f) - mu*mu;
      const float rstd = rsqrtf(var + LN_EPS);
      const int bidx = row >> 11, sI = row & 2047;
      if (mat == 2) {
        const size_t vbase = 2*BHSD + (((size_t)bidx*HH + h)*DD)*SS;
#pragma unroll
        for (int j = 0; j < 4; ++j)
          Xh[vbase + (size_t)(j*16 + l15)*SS + sI] = (__bf16)((x[j] - mu)*rstd*gmv[j] + btv[j]);
      } else {
        const size_t base = (size_t)mat*BHSD + (((size_t)bidx*HH + h)*SS + sI)*DD;
#pragma unroll
        for (int j = 0; j < 4; ++j)
          Xh[base + j*16 + l15] = (__bf16)((x[j] - mu)*rstd*gmv[j] + btv[j]);
      }
    }
}

// ================= flash attention: dbuf + K=32 PV + MFMA row-sum ====================
// r14 structure (dbuf, sigma key-perm, K=32 PV) with the softmax VALU diet:
// (1) Q pre-scaled by log2(e)/181 -> exp2f (native v_exp_f32, no hidden mul);
// (2) l computed by MFMA ones-column: lacc[m] = mfma(pa, ones, lacc) gives
//     D[q][*] = rowsum(p); C/D layout row=4lg+rr matches the epilogue's q index,
//     deleting 32 adds/tile + 2 shfl reduces + 8 shfl broadcasts.
__global__ __launch_bounds__(512) void attn_kernel(const __bf16* Xh, const float* maskF, __bf16* AO) {
  const int qb = blockIdx.x, h = blockIdx.y, b = blockIdx.z;
  const int t = threadIdx.x;
  const int w = t >> 6, lane = t & 63;
  const int hh = w >> 2, wq = w & 3;        // key-half, q-group
  const int l15 = lane & 15, lg = lane >> 4;

  __shared__ char smem[65536];              // [half][buf]{K 8KB, V 8KB} + overlay

  const size_t headoff = (((size_t)b*HH + h)*SS)*DD;
  const __bf16* Qg = Xh + headoff;
  const __bf16* Kg = Xh + BHSD + headoff;
  const __bf16* Vt = Xh + 2*BHSD + (((size_t)b*HH + h)*DD)*SS;   // [D][S]
  const float* qmF = maskF + (size_t)b*SS;
  const float* kmF = maskF + MM + (size_t)b*SS;

  const int q0 = qb*128 + wq*32;

  // Q fragments, pre-scaled by log2(e)/181 (exp2 domain)
  v8bf qf[2][2];
#pragma unroll
  for (int m = 0; m < 2; ++m)
#pragma unroll
    for (int kd = 0; kd < 2; ++kd) {
      v8bf r = *(const v8bf*)(Qg + (size_t)(q0 + m*16 + l15)*DD + kd*32 + lg*8);
      v8bf o;
#pragma unroll
      for (int e = 0; e < 8; ++e) o[e] = (__bf16)((float)r[e] * (SCALE_INV * LOG2E));
      qf[m][kd] = o;
    }

  v8bf onesb;
#pragma unroll
  for (int e = 0; e < 8; ++e) onesb[e] = (__bf16)1.0f;

  v4f O[2][4];
  v4f lacc[2];
  const v4f zf = {0.f,0.f,0.f,0.f};
#pragma unroll
  for (int m = 0; m < 2; ++m) {
    lacc[m] = zf;
#pragma unroll
    for (int df = 0; df < 4; ++df) O[m][df] = zf;
  }

  const int srow = lane >> 3;
  const int sc   = lane & 7;
  // K source row permutation: LDS row r <- global key sig(r).
#define SIGMA(r) (((r) & ~31) | ((((r)>>2)&3)<<3) | ((((r)>>4)&1)<<2) | ((r)&3))
#define STAGE1(BUFC, KT0)                                                                  \
  {                                                                                        \
    char* kb_ = (BUFC);                                                                    \
    char* vb_ = (BUFC) + 8192;                                                             \
    _Pragma("unroll")                                                                      \
    for (int j_ = 0; j_ < 2; ++j_) {                                                       \
      const int r0_ = wq*16 + j_*8;                                                        \
      const int r_  = r0_ + srow;                                                          \
      const int sg_ = SIGMA(r_);                                                           \
      gload_lds16(Kg + (size_t)((KT0) + sg_)*DD + ((sc ^ (r_ & 7))*8), kb_ + r0_*128);     \
      gload_lds16(Vt + (size_t)r_*SS + (KT0) + ((sc ^ (r_ & 7))*8),  vb_ + r0_*128);       \
    }                                                                                      \
  }

  char* bufA = smem + hh*32768;
  char* bufB = bufA + 16384;

  STAGE1(bufA, hh*64);
  __syncthreads();

  for (int tt = 0; tt < 16; ++tt) {
    char* cur = (tt & 1) ? bufB : bufA;
    char* nxt = (tt & 1) ? bufA : bufB;
    if (tt + 1 < 16) STAGE1(nxt, ((tt+1)*2 + hh)*64);   // hides under compute(cur)

    const int kt0 = (tt*2 + hh)*64;
    char* kb = cur;
    char* vb = cur + 8192;

    // ---- K fragments from LDS (swizzled read; rows hold sig-permuted keys) ----
    v8bf kf[4][2];
#pragma unroll
    for (int f = 0; f < 4; ++f)
#pragma unroll
      for (int kd = 0; kd < 2; ++kd) {
        const int rr = f*16 + l15;
        kf[f][kd] = *(const v8bf*)(kb + rr*128 + (((kd*4 + lg) ^ (rr & 7))*16));
      }

    // ---- S^T = K Q^T : lane q=l15; (f,rr) -> global key kt0+sig(f*16+4lg+rr) ----
    v4f st[2][4];
#pragma unroll
    for (int m = 0; m < 2; ++m)
#pragma unroll
      for (int f = 0; f < 4; ++f) st[m][f] = zf;
#pragma unroll
    for (int kd = 0; kd < 2; ++kd)
#pragma unroll
      for (int f = 0; f < 4; ++f)
#pragma unroll
        for (int m = 0; m < 2; ++m)
          st[m][f] = mfma16(kf[f][kd], qf[m][kd], st[m][f]);

    // key-mask for permuted keys: (f,rr) -> (f>>1)*32 + (f&1)*4 + 8*lg + rr (contig in rr)
    v4f km4[4];
#pragma unroll
    for (int f = 0; f < 4; ++f)
      km4[f] = *(const v4f*)(kmF + kt0 + (f >> 1)*32 + (f & 1)*4 + 8*lg);

    // ---- fixed-max softmax (exp2) + PV at K=32 + MFMA row-sum ----
#pragma unroll
    for (int m = 0; m < 2; ++m) {
      float p[4][4];
#pragma unroll
      for (int f = 0; f < 4; ++f)
#pragma unroll
        for (int rr = 0; rr < 4; ++rr)
          p[f][rr] = exp2f(st[m][f][rr]) * km4[f][rr];
#pragma unroll
      for (int g = 0; g < 2; ++g) {
        v8bf pa;
        pa[0] = (__bf16)p[2*g][0];   pa[1] = (__bf16)p[2*g][1];
        pa[2] = (__bf16)p[2*g][2];   pa[3] = (__bf16)p[2*g][3];
        pa[4] = (__bf16)p[2*g+1][0]; pa[5] = (__bf16)p[2*g+1][1];
        pa[6] = (__bf16)p[2*g+1][2]; pa[7] = (__bf16)p[2*g+1][3];
        lacc[m] = mfma16(pa, onesb, lacc[m]);      // rowsum: D[q][*] = sum_k p
#pragma unroll
        for (int df = 0; df < 4; ++df) {
          const int rv = df*16 + l15;
          v8bf vv = *(const v8bf*)(vb + rv*128 + (((g*4 + lg) ^ (rv & 7))*16));
          O[m][df] = mfma16(pa, vv, O[m][df]);
        }
      }
    }
    __syncthreads();   // drains stage(next); protects cur overwrite at tt+2
  }
#undef STAGE1
#undef SIGMA

  // ---- combine halves in LDS (loop ended with barrier) ----
  // lacc layout == O layout: lane holds q = 4*lg+rr (all l15 columns identical).
  float (*Pp)[32][65] = (float (*)[32][65])smem;            // [4][32][65] = 33,280 B
  float (*Lp)[32]     = (float (*)[32])(smem + 4*32*65*4);  // +512 B
  if (hh == 1) {
#pragma unroll
    for (int m = 0; m < 2; ++m)
#pragma unroll
      for (int df = 0; df < 4; ++df)
#pragma unroll
        for (int rr = 0; rr < 4; ++rr)
          Pp[wq][m*16 + 4*lg + rr][df*16 + l15] = O[m][df][rr];
    if (l15 == 0) {
#pragma unroll
      for (int m = 0; m < 2; ++m)
#pragma unroll
        for (int rr = 0; rr < 4; ++rr)
          Lp[wq][m*16 + 4*lg + rr] = lacc[m][rr];
    }
  }
  __syncthreads();
  if (hh == 0) {
#pragma unroll
    for (int m = 0; m < 2; ++m)
#pragma unroll
      for (int df = 0; df < 4; ++df)
#pragma unroll
        for (int rr = 0; rr < 4; ++rr)
          O[m][df][rr] += Pp[wq][m*16 + 4*lg + rr][df*16 + l15];
#pragma unroll
    for (int m = 0; m < 2; ++m)
#pragma unroll
      for (int rr = 0; rr < 4; ++rr) {
        const float lr = lacc[m][rr] + Lp[wq][m*16 + 4*lg + rr];
        const int qrow = q0 + m*16 + 4*lg + rr;
        const float scl = qmF[qrow] / fmaxf(lr, 1e-30f);
#pragma unroll
        for (int df = 0; df < 4; ++df)
          AO[(size_t)(b*SS + qrow)*EE + h*DD + df*16 + l15] = (__bf16)(O[m][df][rr] * scl);
      }
  }
}

// ================= output GEMM: out = (AO @ Wo^T + bo) * qmask =================
// (unchanged from round 11)
__global__ __launch_bounds__(256) void gemm_out(const __bf16* AO, const __bf16* Wb,
                                                const float* bo, const float* maskF, float* out) {
  const int m0 = blockIdx.x * 128;
  const int n0 = blockIdx.y * 128;
  const __bf16* A = AO;
  const __bf16* W = Wb + (size_t)3*EE*EE;   // Wo

  __shared__ char smem[32768];

  const int t = threadIdx.x;
  const int lane = t & 63, w = t >> 6;
  const int wm = w >> 1, wn = w & 1;
  const int l15 = lane & 15, lg = lane >> 4;

  v4f acc[4][4];
  const v4f zf = {0.f,0.f,0.f,0.f};
#pragma unroll
  for (int i = 0; i < 4; ++i)
#pragma unroll
    for (int j = 0; j < 4; ++j) acc[i][j] = zf;

  const int sr0 = (w*64 + lane) >> 2;
  const int sct = (w*64 + lane) & 3;
#define STAGE_PL(BUF, KT)                                                                 \
  {                                                                                       \
    char* ab_ = (BUF);                                                                    \
    char* bb_ = (BUF) + 8192;                                                             \
    _Pragma("unroll")                                                                     \
    for (int j_ = 0; j_ < 2; ++j_) {                                                      \
      const int r_ = sr0 + j_*64;                                                         \
      const int c_ = sct ^ (r_ & 3);                                                      \
      gload_lds16(A + (size_t)(m0 + r_)*EE + (KT) + c_*8, ab_ + j_*4096 + w*1024);        \
      gload_lds16(W + (size_t)(n0 + r_)*EE + (KT) + c_*8, bb_ + j_*4096 + w*1024);        \
    }                                                                                     \
  }

  char* buf0 = smem;
  char* buf1 = smem + 16384;

  STAGE_PL(buf0, 0);
  __syncthreads();

  int cur = 0;
  for (int kt = 0; kt < EE; kt += 32) {
    char* cb = cur ? buf1 : buf0;
    char* nb = cur ? buf0 : buf1;
    if (kt + 32 < EE) STAGE_PL(nb, kt + 32);

    const char* As = cb;
    const char* Bs = cb + 8192;
    v8bf afr[4], bfr[4];
#pragma unroll
    for (int i = 0; i < 4; ++i) {
      const int ra = wm*64 + i*16 + l15;
      afr[i] = *(const v8bf*)(As + ra*64 + ((16*lg) ^ ((ra & 3) << 4)));
      const int rb = wn*64 + i*16 + l15;
      bfr[i] = *(const v8bf*)(Bs + rb*64 + ((16*lg) ^ ((rb & 3) << 4)));
    }
#pragma unroll
    for (int i = 0; i < 4; ++i)
#pragma unroll
      for (int j = 0; j < 4; ++j)
        acc[i][j] = mfma16(afr[i], bfr[j], acc[i][j]);
    __syncthreads();
    cur ^= 1;
  }
#undef STAGE_PL

  float bsv[4]; int ncol[4];
#pragma unroll
  for (int j = 0; j < 4; ++j) {
    ncol[j] = n0 + wn*64 + j*16 + l15;
    bsv[j] = bo[ncol[j]];
  }
#pragma unroll
  for (int i = 0; i < 4; ++i)
#pragma unroll
    for (int rr = 0; rr < 4; ++rr) {
      const int row = m0 + wm*64 + i*16 + 4*lg + rr;
      const float mv = maskF[row];   // query mask
#pragma unroll
      for (int j = 0; j < 4; ++j)
        out[(size_t)row*EE + ncol[j]] = (acc[i][j][rr] + bsv[j]) * mv;
    }
}

// ================= launcher =================
extern "C" void kernel_launch(void* const* d_in, const int* in_sizes, int n_in,
                              void* d_out, int out_size, void* d_ws, size_t ws_size,
                              hipStream_t stream) {
  const float* q  = (const float*)d_in[0];
  const float* k  = (const float*)d_in[1];
  const float* v  = (const float*)d_in[2];
  const float* Wq = (const float*)d_in[3];
  const float* bq = (const float*)d_in[4];
  const float* Wk = (const float*)d_in[5];
  const float* bk = (const float*)d_in[6];
  const float* Wv = (const float*)d_in[7];
  const float* bv = (const float*)d_in[8];
  const float* Wo = (const float*)d_in[9];
  const float* bo = (const float*)d_in[10];
  const float* gq = (const float*)d_in[11];
  const float* betaq = (const float*)d_in[12];
  const float* gk = (const float*)d_in[13];
  const float* betak = (const float*)d_in[14];
  const float* gv = (const float*)d_in[15];
  const float* betav = (const float*)d_in[16];

  char* ws = (char*)d_ws;
  __bf16* Xb = (__bf16*)(ws + oXb);
  __bf16* Wb = (__bf16*)(ws + oWb);
  __bf16* Xh = (__bf16*)(ws + oXh);
  __bf16* AO = (__bf16*)(ws + oAO);
  float*  maskF = (float*)(ws + oMk);

  mask_kernel<<<dim3(96), dim3(256), 0, stream>>>(d_in[17], d_in[18], d_in[19], maskF);
  convert_kernel<<<dim3(13312), dim3(256), 0, stream>>>(q, k, v, Wq, Wk, Wv, Wo, Xb, Wb);
  gemm_proj_ln<<<dim3(64, 4, 3), dim3(256), 0, stream>>>(Xb, Wb, bq, bk, bv,
                                                         gq, betaq, gk, betak, gv, betav,
                                                         maskF, Xh);
  attn_kernel<<<dim3(16, 8, 4), dim3(512), 0, stream>>>(Xh, maskF, AO);
  gemm_out<<<dim3(64, 4, 1), dim3(256), 0, stream>>>(AO, Wb, bo, maskF, (float*)d_out);
}

// Round 16
// 117.494 us; speedup vs baseline: 1.0616x; 1.0616x over previous
//
#include <hip/hip_runtime.h>
#include <cstdint>
#include <cstddef>

// ---------------- problem constants ----------------
#define BB 4
#define SS 2048
#define EE 512
#define HH 8
#define DD 64
#define MM (BB*SS)                       // 8192 token rows
#define BHSD ((size_t)BB*HH*SS*DD)       // 4194304 elements per q/k/v head tensor

static constexpr float SCALE_INV = 1.0f / 181.0f;   // SCALE = float(512 // 8**0.5) = 181.0
static constexpr float LOG2E = 1.4426950408889634f;
static constexpr float LN_EPS = 1e-5f;

typedef float  v4f  __attribute__((ext_vector_type(4)));
typedef __bf16 v8bf __attribute__((ext_vector_type(8)));
typedef __bf16 v4bf __attribute__((ext_vector_type(4)));
typedef short  s4   __attribute__((ext_vector_type(4)));

static __device__ __forceinline__ v4f mfma16(v8bf a, v8bf b, v4f c) {
  return __builtin_amdgcn_mfma_f32_16x16x32_bf16(a, b, c, 0, 0, 0);
}

// native 2^x (v_exp_f32). r15 used libm exp2f -> __ocml_exp2_f32 with denormal
// handling (~10 VALU ops) -> VALUBusy 47.6->57.5 and a 9us regression. The
// builtin is the single instruction; fallback costs one extra mul only.
static __device__ __forceinline__ float fexp2(float x) {
#if __has_builtin(__builtin_amdgcn_exp2f)
  return __builtin_amdgcn_exp2f(x);
#else
  return __expf(x * 0.6931471805599453f);
#endif
}

// async global->LDS, 16B per lane; LDS dest = wave-uniform base + lane*16 (HW rule).
typedef const void __attribute__((address_space(1))) gas_void;
typedef void __attribute__((address_space(3))) las_void;
static __device__ __forceinline__ void gload_lds16(const void* g, void* l) {
  __builtin_amdgcn_global_load_lds((gas_void*)g, (las_void*)l, 16, 0, 0);
}

// ---------------- workspace layout (bytes) ----------------
static constexpr size_t oXb = 0;
static constexpr size_t oWb = oXb + (size_t)3*MM*EE*2;
static constexpr size_t oXh = oWb + (size_t)4*EE*EE*2;
static constexpr size_t oAO = oXh + (size_t)3*MM*EE*2;
static constexpr size_t oMk = oAO + (size_t)MM*EE*2;

// ================= mask canonicalization (parallel) =================
__global__ void mask_kernel(const void* qm, const void* km, const void* vm, float* maskF) {
  __shared__ int s_n01, s_nF;
  const int t = threadIdx.x;
  if (t == 0) { s_n01 = 0; s_nF = 0; }
  __syncthreads();
  int n01 = 0, nF = 0;
  const unsigned* wq = (const unsigned*)qm;
  for (int i = t; i < 2048; i += 256) {
    const unsigned u = wq[i];
    if (u != 0u && u != 1u) n01 = 1;
    if (u != 0u && u != 0x3F800000u) nF = 1;
  }
  if (n01) atomicOr(&s_n01, 1);
  if (nF)  atomicOr(&s_nF, 1);
  __syncthreads();
  const int mode = (!s_n01) ? 0 : (!s_nF) ? 1 : 2;   // 0=i32, 1=f32, 2=u8
  const int gidx = blockIdx.x * 256 + t;
  const int m = gidx / MM, i = gidx % MM;
  const void* p = (m == 0) ? qm : (m == 1) ? km : vm;
  int v;
  if (mode == 0)      v = (((const int*)p)[i] != 0);
  else if (mode == 1) v = (((const unsigned*)p)[i] != 0u);
  else                v = (((const unsigned char*)p)[i] != 0);
  maskF[m*MM + i] = v ? 1.0f : 0.0f;
}

// ================= fp32 -> bf16 convert =================
__global__ void convert_kernel(const float* q, const float* k, const float* v,
                               const float* Wq, const float* Wk, const float* Wv, const float* Wo,
                               __bf16* Xb, __bf16* Wb) {
  const long idx = (long)blockIdx.x * 256 + threadIdx.x;     // in float4 units
  const long NX4 = (long)3*MM*EE/4;
  const long NW4 = (long)4*EE*EE/4;
  if (idx < NX4) {
    const long per = (long)MM*EE/4;
    const long mat = idx / per, off = idx % per;
    const float* src = (mat == 0) ? q : (mat == 1) ? k : v;
    v4f val = ((const v4f*)src)[off];
    v4bf o; o[0]=(__bf16)val[0]; o[1]=(__bf16)val[1]; o[2]=(__bf16)val[2]; o[3]=(__bf16)val[3];
    ((v4bf*)Xb)[idx] = o;
  } else if (idx < NX4 + NW4) {
    const long j = idx - NX4;
    const long per = (long)EE*EE/4;
    const long mat = j / per, off = j % per;
    const float* src = (mat == 0) ? Wq : (mat == 1) ? Wk : (mat == 2) ? Wv : Wo;
    v4f val = ((const v4f*)src)[off];
    v4bf o; o[0]=(__bf16)val[0]; o[1]=(__bf16)val[1]; o[2]=(__bf16)val[2]; o[3]=(__bf16)val[3];
    ((v4bf*)Wb)[j] = o;
  }
}

// ===== projection GEMM + bias + mask + per-head LayerNorm, fused =====
// (unchanged from round 11 -- m97-style 2-phase, passing)
__global__ __launch_bounds__(256) void gemm_proj_ln(const __bf16* Xb, const __bf16* Wb,
                                                    const float* bq, const float* bk, const float* bv,
                                                    const float* gq, const float* betaq,
                                                    const float* gk, const float* betak,
                                                    const float* gv, const float* betav,
                                                    const float* maskF, __bf16* Xh) {
  const int m0  = blockIdx.x * 128;
  const int n0  = blockIdx.y * 128;
  const int mat = blockIdx.z;
  const __bf16* A = Xb + (size_t)mat*MM*EE;
  const __bf16* W = Wb + (size_t)mat*EE*EE;
  const float* bias = (mat == 0) ? bq : (mat == 1) ? bk : bv;
  const float* gam  = (mat == 0) ? gq : (mat == 1) ? gk : gv;
  const float* bet  = (mat == 0) ? betaq : (mat == 1) ? betak : betav;

  __shared__ char smem[32768];   // [buf][A 8KB | B 8KB]

  const int t = threadIdx.x;
  const int lane = t & 63, w = t >> 6;
  const int wm = w >> 1, wn = w & 1;
  const int l15 = lane & 15, lg = lane >> 4;

  v4f acc[4][4];
  const v4f zf = {0.f, 0.f, 0.f, 0.f};
#pragma unroll
  for (int i = 0; i < 4; ++i)
#pragma unroll
    for (int j = 0; j < 4; ++j) acc[i][j] = zf;

  const int sr0 = (w*64 + lane) >> 2;
  const int sct = (w*64 + lane) & 3;
#define STAGE_PL(BUF, KT)                                                                 \
  {                                                                                       \
    char* ab_ = (BUF);                                                                    \
    char* bb_ = (BUF) + 8192;                                                             \
    _Pragma("unroll")                                                                     \
    for (int j_ = 0; j_ < 2; ++j_) {                                                      \
      const int r_ = sr0 + j_*64;                                                         \
      const int c_ = sct ^ (r_ & 3);                                                      \
      gload_lds16(A + (size_t)(m0 + r_)*EE + (KT) + c_*8, ab_ + j_*4096 + w*1024);        \
      gload_lds16(W + (size_t)(n0 + r_)*EE + (KT) + c_*8, bb_ + j_*4096 + w*1024);        \
    }                                                                                     \
  }

  char* buf0 = smem;
  char* buf1 = smem + 16384;

  STAGE_PL(buf0, 0);
  __syncthreads();

  int cur = 0;
  for (int kt = 0; kt < EE; kt += 32) {
    char* cb = cur ? buf1 : buf0;
    char* nb = cur ? buf0 : buf1;
    if (kt + 32 < EE) STAGE_PL(nb, kt + 32);

    const char* As = cb;
    const char* Bs = cb + 8192;
    v8bf afr[4], bfr[4];
#pragma unroll
    for (int i = 0; i < 4; ++i) {
      const int ra = wm*64 + i*16 + l15;
      afr[i] = *(const v8bf*)(As + ra*64 + ((16*lg) ^ ((ra & 3) << 4)));
      const int rb = wn*64 + i*16 + l15;
      bfr[i] = *(const v8bf*)(Bs + rb*64 + ((16*lg) ^ ((rb & 3) << 4)));
    }
#pragma unroll
    for (int i = 0; i < 4; ++i)
#pragma unroll
      for (int j = 0; j < 4; ++j)
        acc[i][j] = mfma16(afr[i], bfr[j], acc[i][j]);
    __syncthreads();
    cur ^= 1;
  }
#undef STAGE_PL

  const int nbase = n0 + wn*64;          // 64-aligned => one head
  const int h = nbase >> 6;
  float bsv[4], gmv[4], btv[4];
#pragma unroll
  for (int j = 0; j < 4; ++j) {
    const int d = j*16 + l15;
    bsv[j] = bias[nbase + d];
    gmv[j] = gam[d];
    btv[j] = bet[d];
  }
#pragma unroll
  for (int i = 0; i < 4; ++i)
#pragma unroll
    for (int rr = 0; rr < 4; ++rr) {
      const int row = m0 + wm*64 + i*16 + 4*lg + rr;
      const float mv = maskF[mat*MM + row];
      float x[4];
      float s = 0.f, s2 = 0.f;
#pragma unroll
      for (int j = 0; j < 4; ++j) {
        x[j] = (acc[i][j][rr] + bsv[j]) * mv;
        s += x[j]; s2 += x[j]*x[j];
      }
      s  += __shfl_xor(s, 1, 64);  s  += __shfl_xor(s, 2, 64);
      s  += __shfl_xor(s, 4, 64);  s  += __shfl_xor(s, 8, 64);
      s2 += __shfl_xor(s2, 1, 64); s2 += __shfl_xor(s2, 2, 64);
      s2 += __shfl_xor(s2, 4, 64); s2 += __shfl_xor(s2, 8, 64);
      const float mu  = s * (1.0f/64.0f);
      const float var = s2 * (1.0f/64.0f) - mu*mu;
      const float rstd = rsqrtf(var + LN_EPS);
      const int bidx = row >> 11, sI = row & 2047;
      if (mat == 2) {
        const size_t vbase = 2*BHSD + (((size_t)bidx*HH + h)*DD)*SS;
#pragma unroll
        for (int j = 0; j < 4; ++j)
          Xh[vbase + (size_t)(j*16 + l15)*SS + sI] = (__bf16)((x[j] - mu)*rstd*gmv[j] + btv[j]);
      } else {
        const size_t base = (size_t)mat*BHSD + (((size_t)bidx*HH + h)*SS + sI)*DD;
#pragma unroll
        for (int j = 0; j < 4; ++j)
          Xh[base + j*16 + l15] = (__bf16)((x[j] - mu)*rstd*gmv[j] + btv[j]);
      }
    }
}

// ================= flash attention: dbuf + K=32 PV + MFMA row-sum + native exp2 =========
// r14 structure (dbuf, sigma key-perm, K=32 PV) + r15's MFMA ones-column row-sum
// + NATIVE v_exp_f32 via builtin (the r15 regression was libm exp2f's denormal path).
__global__ __launch_bounds__(512) void attn_kernel(const __bf16* Xh, const float* maskF, __bf16* AO) {
  const int qb = blockIdx.x, h = blockIdx.y, b = blockIdx.z;
  const int t = threadIdx.x;
  const int w = t >> 6, lane = t & 63;
  const int hh = w >> 2, wq = w & 3;        // key-half, q-group
  const int l15 = lane & 15, lg = lane >> 4;

  __shared__ char smem[65536];              // [half][buf]{K 8KB, V 8KB} + overlay

  const size_t headoff = (((size_t)b*HH + h)*SS)*DD;
  const __bf16* Qg = Xh + headoff;
  const __bf16* Kg = Xh + BHSD + headoff;
  const __bf16* Vt = Xh + 2*BHSD + (((size_t)b*HH + h)*DD)*SS;   // [D][S]
  const float* qmF = maskF + (size_t)b*SS;
  const float* kmF = maskF + MM + (size_t)b*SS;

  const int q0 = qb*128 + wq*32;

  // Q fragments, pre-scaled by log2(e)/181 (exp2 domain)
  v8bf qf[2][2];
#pragma unroll
  for (int m = 0; m < 2; ++m)
#pragma unroll
    for (int kd = 0; kd < 2; ++kd) {
      v8bf r = *(const v8bf*)(Qg + (size_t)(q0 + m*16 + l15)*DD + kd*32 + lg*8);
      v8bf o;
#pragma unroll
      for (int e = 0; e < 8; ++e) o[e] = (__bf16)((float)r[e] * (SCALE_INV * LOG2E));
      qf[m][kd] = o;
    }

  v8bf onesb;
#pragma unroll
  for (int e = 0; e < 8; ++e) onesb[e] = (__bf16)1.0f;

  v4f O[2][4];
  v4f lacc[2];
  const v4f zf = {0.f,0.f,0.f,0.f};
#pragma unroll
  for (int m = 0; m < 2; ++m) {
    lacc[m] = zf;
#pragma unroll
    for (int df = 0; df < 4; ++df) O[m][df] = zf;
  }

  const int srow = lane >> 3;
  const int sc   = lane & 7;
  // K source row permutation: LDS row r <- global key sig(r).
#define SIGMA(r) (((r) & ~31) | ((((r)>>2)&3)<<3) | ((((r)>>4)&1)<<2) | ((r)&3))
#define STAGE1(BUFC, KT0)                                                                  \
  {                                                                                        \
    char* kb_ = (BUFC);                                                                    \
    char* vb_ = (BUFC) + 8192;                                                             \
    _Pragma("unroll")                                                                      \
    for (int j_ = 0; j_ < 2; ++j_) {                                                       \
      const int r0_ = wq*16 + j_*8;                                                        \
      const int r_  = r0_ + srow;                                                          \
      const int sg_ = SIGMA(r_);                                                           \
      gload_lds16(Kg + (size_t)((KT0) + sg_)*DD + ((sc ^ (r_ & 7))*8), kb_ + r0_*128);     \
      gload_lds16(Vt + (size_t)r_*SS + (KT0) + ((sc ^ (r_ & 7))*8),  vb_ + r0_*128);       \
    }                                                                                      \
  }

  char* bufA = smem + hh*32768;
  char* bufB = bufA + 16384;

  STAGE1(bufA, hh*64);
  __syncthreads();

  for (int tt = 0; tt < 16; ++tt) {
    char* cur = (tt & 1) ? bufB : bufA;
    char* nxt = (tt & 1) ? bufA : bufB;
    if (tt + 1 < 16) STAGE1(nxt, ((tt+1)*2 + hh)*64);   // hides under compute(cur)

    const int kt0 = (tt*2 + hh)*64;
    char* kb = cur;
    char* vb = cur + 8192;

    // ---- K fragments from LDS (swizzled read; rows hold sig-permuted keys) ----
    v8bf kf[4][2];
#pragma unroll
    for (int f = 0; f < 4; ++f)
#pragma unroll
      for (int kd = 0; kd < 2; ++kd) {
        const int rr = f*16 + l15;
        kf[f][kd] = *(const v8bf*)(kb + rr*128 + (((kd*4 + lg) ^ (rr & 7))*16));
      }

    // ---- S^T = K Q^T : lane q=l15; (f,rr) -> global key kt0+sig(f*16+4lg+rr) ----
    v4f st[2][4];
#pragma unroll
    for (int m = 0; m < 2; ++m)
#pragma unroll
      for (int f = 0; f < 4; ++f) st[m][f] = zf;
#pragma unroll
    for (int kd = 0; kd < 2; ++kd)
#pragma unroll
      for (int f = 0; f < 4; ++f)
#pragma unroll
        for (int m = 0; m < 2; ++m)
          st[m][f] = mfma16(kf[f][kd], qf[m][kd], st[m][f]);

    // key-mask for permuted keys: (f,rr) -> (f>>1)*32 + (f&1)*4 + 8*lg + rr (contig in rr)
    v4f km4[4];
#pragma unroll
    for (int f = 0; f < 4; ++f)
      km4[f] = *(const v4f*)(kmF + kt0 + (f >> 1)*32 + (f & 1)*4 + 8*lg);

    // ---- fixed-max softmax (native exp2) + PV at K=32 + MFMA row-sum ----
#pragma unroll
    for (int m = 0; m < 2; ++m) {
      float p[4][4];
#pragma unroll
      for (int f = 0; f < 4; ++f)
#pragma unroll
        for (int rr = 0; rr < 4; ++rr)
          p[f][rr] = fexp2(st[m][f][rr]) * km4[f][rr];
#pragma unroll
      for (int g = 0; g < 2; ++g) {
        v8bf pa;
        pa[0] = (__bf16)p[2*g][0];   pa[1] = (__bf16)p[2*g][1];
        pa[2] = (__bf16)p[2*g][2];   pa[3] = (__bf16)p[2*g][3];
        pa[4] = (__bf16)p[2*g+1][0]; pa[5] = (__bf16)p[2*g+1][1];
        pa[6] = (__bf16)p[2*g+1][2]; pa[7] = (__bf16)p[2*g+1][3];
        lacc[m] = mfma16(pa, onesb, lacc[m]);      // rowsum: D[q][*] = sum_k p
#pragma unroll
        for (int df = 0; df < 4; ++df) {
          const int rv = df*16 + l15;
          v8bf vv = *(const v8bf*)(vb + rv*128 + (((g*4 + lg) ^ (rv & 7))*16));
          O[m][df] = mfma16(pa, vv, O[m][df]);
        }
      }
    }
    __syncthreads();   // drains stage(next); protects cur overwrite at tt+2
  }
#undef STAGE1
#undef SIGMA

  // ---- combine halves in LDS (loop ended with barrier) ----
  // lacc layout == O layout: lane holds q = 4*lg+rr (all l15 columns identical).
  float (*Pp)[32][65] = (float (*)[32][65])smem;            // [4][32][65] = 33,280 B
  float (*Lp)[32]     = (float (*)[32])(smem + 4*32*65*4);  // +512 B
  if (hh == 1) {
#pragma unroll
    for (int m = 0; m < 2; ++m)
#pragma unroll
      for (int df = 0; df < 4; ++df)
#pragma unroll
        for (int rr = 0; rr < 4; ++rr)
          Pp[wq][m*16 + 4*lg + rr][df*16 + l15] = O[m][df][rr];
    if (l15 == 0) {
#pragma unroll
      for (int m = 0; m < 2; ++m)
#pragma unroll
        for (int rr = 0; rr < 4; ++rr)
          Lp[wq][m*16 + 4*lg + rr] = lacc[m][rr];
    }
  }
  __syncthreads();
  if (hh == 0) {
#pragma unroll
    for (int m = 0; m < 2; ++m)
#pragma unroll
      for (int df = 0; df < 4; ++df)
#pragma unroll
        for (int rr = 0; rr < 4; ++rr)
          O[m][df][rr] += Pp[wq][m*16 + 4*lg + rr][df*16 + l15];
#pragma unroll
    for (int m = 0; m < 2; ++m)
#pragma unroll
      for (int rr = 0; rr < 4; ++rr) {
        const float lr = lacc[m][rr] + Lp[wq][m*16 + 4*lg + rr];
        const int qrow = q0 + m*16 + 4*lg + rr;
        const float scl = qmF[qrow] / fmaxf(lr, 1e-30f);
#pragma unroll
        for (int df = 0; df < 4; ++df)
          AO[(size_t)(b*SS + qrow)*EE + h*DD + df*16 + l15] = (__bf16)(O[m][df][rr] * scl);
      }
  }
}

// ================= output GEMM: out = (AO @ Wo^T + bo) * qmask =================
// (unchanged from round 11)
__global__ __launch_bounds__(256) void gemm_out(const __bf16* AO, const __bf16* Wb,
                                                const float* bo, const float* maskF, float* out) {
  const int m0 = blockIdx.x * 128;
  const int n0 = blockIdx.y * 128;
  const __bf16* A = AO;
  const __bf16* W = Wb + (size_t)3*EE*EE;   // Wo

  __shared__ char smem[32768];

  const int t = threadIdx.x;
  const int lane = t & 63, w = t >> 6;
  const int wm = w >> 1, wn = w & 1;
  const int l15 = lane & 15, lg = lane >> 4;

  v4f acc[4][4];
  const v4f zf = {0.f,0.f,0.f,0.f};
#pragma unroll
  for (int i = 0; i < 4; ++i)
#pragma unroll
    for (int j = 0; j < 4; ++j) acc[i][j] = zf;

  const int sr0 = (w*64 + lane) >> 2;
  const int sct = (w*64 + lane) & 3;
#define STAGE_PL(BUF, KT)                                                                 \
  {                                                                                       \
    char* ab_ = (BUF);                                                                    \
    char* bb_ = (BUF) + 8192;                                                             \
    _Pragma("unroll")                                                                     \
    for (int j_ = 0; j_ < 2; ++j_) {                                                      \
      const int r_ = sr0 + j_*64;                                                         \
      const int c_ = sct ^ (r_ & 3);                                                      \
      gload_lds16(A + (size_t)(m0 + r_)*EE + (KT) + c_*8, ab_ + j_*4096 + w*1024);        \
      gload_lds16(W + (size_t)(n0 + r_)*EE + (KT) + c_*8, bb_ + j_*4096 + w*1024);        \
    }                                                                                     \
  }

  char* buf0 = smem;
  char* buf1 = smem + 16384;

  STAGE_PL(buf0, 0);
  __syncthreads();

  int cur = 0;
  for (int kt = 0; kt < EE; kt += 32) {
    char* cb = cur ? buf1 : buf0;
    char* nb = cur ? buf0 : buf1;
    if (kt + 32 < EE) STAGE_PL(nb, kt + 32);

    const char* As = cb;
    const char* Bs = cb + 8192;
    v8bf afr[4], bfr[4];
#pragma unroll
    for (int i = 0; i < 4; ++i) {
      const int ra = wm*64 + i*16 + l15;
      afr[i] = *(const v8bf*)(As + ra*64 + ((16*lg) ^ ((ra & 3) << 4)));
      const int rb = wn*64 + i*16 + l15;
      bfr[i] = *(const v8bf*)(Bs + rb*64 + ((16*lg) ^ ((rb & 3) << 4)));
    }
#pragma unroll
    for (int i = 0; i < 4; ++i)
#pragma unroll
      for (int j = 0; j < 4; ++j)
        acc[i][j] = mfma16(afr[i], bfr[j], acc[i][j]);
    __syncthreads();
    cur ^= 1;
  }
#undef STAGE_PL

  float bsv[4]; int ncol[4];
#pragma unroll
  for (int j = 0; j < 4; ++j) {
    ncol[j] = n0 + wn*64 + j*16 + l15;
    bsv[j] = bo[ncol[j]];
  }
#pragma unroll
  for (int i = 0; i < 4; ++i)
#pragma unroll
    for (int rr = 0; rr < 4; ++rr) {
      const int row = m0 + wm*64 + i*16 + 4*lg + rr;
      const float mv = maskF[row];   // query mask
#pragma unroll
      for (int j = 0; j < 4; ++j)
        out[(size_t)row*EE + ncol[j]] = (acc[i][j][rr] + bsv[j]) * mv;
    }
}

// ================= launcher =================
extern "C" void kernel_launch(void* const* d_in, const int* in_sizes, int n_in,
                              void* d_out, int out_size, void* d_ws, size_t ws_size,
                              hipStream_t stream) {
  const float* q  = (const float*)d_in[0];
  const float* k  = (const float*)d_in[1];
  const float* v  = (const float*)d_in[2];
  const float* Wq = (const float*)d_in[3];
  const float* bq = (const float*)d_in[4];
  const float* Wk = (const float*)d_in[5];
  const float* bk = (const float*)d_in[6];
  const float* Wv = (const float*)d_in[7];
  const float* bv = (const float*)d_in[8];
  const float* Wo = (const float*)d_in[9];
  const float* bo = (const float*)d_in[10];
  const float* gq = (const float*)d_in[11];
  const float* betaq = (const float*)d_in[12];
  const float* gk = (const float*)d_in[13];
  const float* betak = (const float*)d_in[14];
  const float* gv = (const float*)d_in[15];
  const float* betav = (const float*)d_in[16];

  char* ws = (char*)d_ws;
  __bf16* Xb = (__bf16*)(ws + oXb);
  __bf16* Wb = (__bf16*)(ws + oWb);
  __bf16* Xh = (__bf16*)(ws + oXh);
  __bf16* AO = (__bf16*)(ws + oAO);
  float*  maskF = (float*)(ws + oMk);

  mask_kernel<<<dim3(96), dim3(256), 0, stream>>>(d_in[17], d_in[18], d_in[19], maskF);
  convert_kernel<<<dim3(13312), dim3(256), 0, stream>>>(q, k, v, Wq, Wk, Wv, Wo, Xb, Wb);
  gemm_proj_ln<<<dim3(64, 4, 3), dim3(256), 0, stream>>>(Xb, Wb, bq, bk, bv,
                                                         gq, betaq, gk, betak, gv, betav,
                                                         maskF, Xh);
  attn_kernel<<<dim3(16, 8, 4), dim3(512), 0, stream>>>(Xh, maskF, AO);
  gemm_out<<<dim3(64, 4, 1), dim3(256), 0, stream>>>(AO, Wb, bo, maskF, (float*)d_out);
}

// Round 18
// 114.903 us; speedup vs baseline: 1.0855x; 1.0226x over previous
//
#include <hip/hip_runtime.h>
#include <cstdint>
#include <cstddef>

// ---------------- problem constants ----------------
#define BB 4
#define SS 2048
#define EE 512
#define HH 8
#define DD 64
#define MM (BB*SS)                       // 8192 token rows
#define BHSD ((size_t)BB*HH*SS*DD)       // 4194304 elements per q/k/v head tensor

static constexpr float SCALE_INV = 1.0f / 181.0f;   // SCALE = float(512 // 8**0.5) = 181.0
static constexpr float LOG2E = 1.4426950408889634f;
static constexpr float LN_EPS = 1e-5f;

typedef float  v4f  __attribute__((ext_vector_type(4)));
typedef __bf16 v8bf __attribute__((ext_vector_type(8)));
typedef __bf16 v4bf __attribute__((ext_vector_type(4)));
typedef short  s4   __attribute__((ext_vector_type(4)));

static __device__ __forceinline__ v4f mfma16(v8bf a, v8bf b, v4f c) {
  return __builtin_amdgcn_mfma_f32_16x16x32_bf16(a, b, c, 0, 0, 0);
}

// native 2^x (v_exp_f32); libm exp2f regressed (r15: denormal path).
static __device__ __forceinline__ float fexp2(float x) {
#if __has_builtin(__builtin_amdgcn_exp2f)
  return __builtin_amdgcn_exp2f(x);
#else
  return __expf(x * 0.6931471805599453f);
#endif
}

// async global->LDS, 16B per lane; LDS dest = wave-uniform base + lane*16 (HW rule).
typedef const void __attribute__((address_space(1))) gas_void;
typedef void __attribute__((address_space(3))) las_void;
static __device__ __forceinline__ void gload_lds16(const void* g, void* l) {
  __builtin_amdgcn_global_load_lds((gas_void*)g, (las_void*)l, 16, 0, 0);
}

// ---------------- workspace layout (bytes) ----------------
static constexpr size_t oXb = 0;
static constexpr size_t oWb = oXb + (size_t)3*MM*EE*2;
static constexpr size_t oXh = oWb + (size_t)4*EE*EE*2;
static constexpr size_t oAO = oXh + (size_t)3*MM*EE*2;
static constexpr size_t oMk = oAO + (size_t)MM*EE*2;

// ================= mask canonicalization (parallel) =================
__global__ void mask_kernel(const void* qm, const void* km, const void* vm, float* maskF) {
  __shared__ int s_n01, s_nF;
  const int t = threadIdx.x;
  if (t == 0) { s_n01 = 0; s_nF = 0; }
  __syncthreads();
  int n01 = 0, nF = 0;
  const unsigned* wq = (const unsigned*)qm;
  for (int i = t; i < 2048; i += 256) {
    const unsigned u = wq[i];
    if (u != 0u && u != 1u) n01 = 1;
    if (u != 0u && u != 0x3F800000u) nF = 1;
  }
  if (n01) atomicOr(&s_n01, 1);
  if (nF)  atomicOr(&s_nF, 1);
  __syncthreads();
  const int mode = (!s_n01) ? 0 : (!s_nF) ? 1 : 2;   // 0=i32, 1=f32, 2=u8
  const int gidx = blockIdx.x * 256 + t;
  const int m = gidx / MM, i = gidx % MM;
  const void* p = (m == 0) ? qm : (m == 1) ? km : vm;
  int v;
  if (mode == 0)      v = (((const int*)p)[i] != 0);
  else if (mode == 1) v = (((const unsigned*)p)[i] != 0u);
  else                v = (((const unsigned char*)p)[i] != 0);
  maskF[m*MM + i] = v ? 1.0f : 0.0f;
}

// ================= fp32 -> bf16 convert =================
__global__ void convert_kernel(const float* q, const float* k, const float* v,
                               const float* Wq, const float* Wk, const float* Wv, const float* Wo,
                               __bf16* Xb, __bf16* Wb) {
  const long idx = (long)blockIdx.x * 256 + threadIdx.x;     // in float4 units
  const long NX4 = (long)3*MM*EE/4;
  const long NW4 = (long)4*EE*EE/4;
  if (idx < NX4) {
    const long per = (long)MM*EE/4;
    const long mat = idx / per, off = idx % per;
    const float* src = (mat == 0) ? q : (mat == 1) ? k : v;
    v4f val = ((const v4f*)src)[off];
    v4bf o; o[0]=(__bf16)val[0]; o[1]=(__bf16)val[1]; o[2]=(__bf16)val[2]; o[3]=(__bf16)val[3];
    ((v4bf*)Xb)[idx] = o;
  } else if (idx < NX4 + NW4) {
    const long j = idx - NX4;
    const long per = (long)EE*EE/4;
    const long mat = j / per, off = j % per;
    const float* src = (mat == 0) ? Wq : (mat == 1) ? Wk : (mat == 2) ? Wv : Wo;
    v4f val = ((const v4f*)src)[off];
    v4bf o; o[0]=(__bf16)val[0]; o[1]=(__bf16)val[1]; o[2]=(__bf16)val[2]; o[3]=(__bf16)val[3];
    ((v4bf*)Wb)[j] = o;
  }
}

// ===== projection GEMM + bias + mask + per-head LayerNorm, fused =====
// (unchanged from round 11 -- m97-style 2-phase, passing)
__global__ __launch_bounds__(256) void gemm_proj_ln(const __bf16* Xb, const __bf16* Wb,
                                                    const float* bq, const float* bk, const float* bv,
                                                    const float* gq, const float* betaq,
                                                    const float* gk, const float* betak,
                                                    const float* gv, const float* betav,
                                                    const float* maskF, __bf16* Xh) {
  const int m0  = blockIdx.x * 128;
  const int n0  = blockIdx.y * 128;
  const int mat = blockIdx.z;
  const __bf16* A = Xb + (size_t)mat*MM*EE;
  const __bf16* W = Wb + (size_t)mat*EE*EE;
  const float* bias = (mat == 0) ? bq : (mat == 1) ? bk : bv;
  const float* gam  = (mat == 0) ? gq : (mat == 1) ? gk : gv;
  const float* bet  = (mat == 0) ? betaq : (mat == 1) ? betak : betav;

  __shared__ char smem[32768];   // [buf][A 8KB | B 8KB]

  const int t = threadIdx.x;
  const int lane = t & 63, w = t >> 6;
  const int wm = w >> 1, wn = w & 1;
  const int l15 = lane & 15, lg = lane >> 4;

  v4f acc[4][4];
  const v4f zf = {0.f, 0.f, 0.f, 0.f};
#pragma unroll
  for (int i = 0; i < 4; ++i)
#pragma unroll
    for (int j = 0; j < 4; ++j) acc[i][j] = zf;

  const int sr0 = (w*64 + lane) >> 2;
  const int sct = (w*64 + lane) & 3;
#define STAGE_PL(BUF, KT)                                                                 \
  {                                                                                       \
    char* ab_ = (BUF);                                                                    \
    char* bb_ = (BUF) + 8192;                                                             \
    _Pragma("unroll")                                                                     \
    for (int j_ = 0; j_ < 2; ++j_) {                                                      \
      const int r_ = sr0 + j_*64;                                                         \
      const int c_ = sct ^ (r_ & 3);                                                      \
      gload_lds16(A + (size_t)(m0 + r_)*EE + (KT) + c_*8, ab_ + j_*4096 + w*1024);        \
      gload_lds16(W + (size_t)(n0 + r_)*EE + (KT) + c_*8, bb_ + j_*4096 + w*1024);        \
    }                                                                                     \
  }

  char* buf0 = smem;
  char* buf1 = smem + 16384;

  STAGE_PL(buf0, 0);
  __syncthreads();

  int cur = 0;
  for (int kt = 0; kt < EE; kt += 32) {
    char* cb = cur ? buf1 : buf0;
    char* nb = cur ? buf0 : buf1;
    if (kt + 32 < EE) STAGE_PL(nb, kt + 32);

    const char* As = cb;
    const char* Bs = cb + 8192;
    v8bf afr[4], bfr[4];
#pragma unroll
    for (int i = 0; i < 4; ++i) {
      const int ra = wm*64 + i*16 + l15;
      afr[i] = *(const v8bf*)(As + ra*64 + ((16*lg) ^ ((ra & 3) << 4)));
      const int rb = wn*64 + i*16 + l15;
      bfr[i] = *(const v8bf*)(Bs + rb*64 + ((16*lg) ^ ((rb & 3) << 4)));
    }
#pragma unroll
    for (int i = 0; i < 4; ++i)
#pragma unroll
      for (int j = 0; j < 4; ++j)
        acc[i][j] = mfma16(afr[i], bfr[j], acc[i][j]);
    __syncthreads();
    cur ^= 1;
  }
#undef STAGE_PL

  const int nbase = n0 + wn*64;          // 64-aligned => one head
  const int h = nbase >> 6;
  float bsv[4], gmv[4], btv[4];
#pragma unroll
  for (int j = 0; j < 4; ++j) {
    const int d = j*16 + l15;
    bsv[j] = bias[nbase + d];
    gmv[j] = gam[d];
    btv[j] = bet[d];
  }
#pragma unroll
  for (int i = 0; i < 4; ++i)
#pragma unroll
    for (int rr = 0; rr < 4; ++rr) {
      const int row = m0 + wm*64 + i*16 + 4*lg + rr;
      const float mv = maskF[mat*MM + row];
      float x[4];
      float s = 0.f, s2 = 0.f;
#pragma unroll
      for (int j = 0; j < 4; ++j) {
        x[j] = (acc[i][j][rr] + bsv[j]) * mv;
        s += x[j]; s2 += x[j]*x[j];
      }
      s  += __shfl_xor(s, 1, 64);  s  += __shfl_xor(s, 2, 64);
      s  += __shfl_xor(s, 4, 64);  s  += __shfl_xor(s, 8, 64);
      s2 += __shfl_xor(s2, 1, 64); s2 += __shfl_xor(s2, 2, 64);
      s2 += __shfl_xor(s2, 4, 64); s2 += __shfl_xor(s2, 8, 64);
      const float mu  = s * (1.0f/64.0f);
      const float var = s2 * (1.0f/64.0f) - mu*mu;
      const float rstd = rsqrtf(var + LN_EPS);
      const int bidx = row >> 11, sI = row & 2047;
      if (mat == 2) {
        const size_t vbase = 2*BHSD + (((size_t)bidx*HH + h)*DD)*SS;
#pragma unroll
        for (int j = 0; j < 4; ++j)
          Xh[vbase + (size_t)(j*16 + l15)*SS + sI] = (__bf16)((x[j] - mu)*rstd*gmv[j] + btv[j]);
      } else {
        const size_t base = (size_t)mat*BHSD + (((size_t)bidx*HH + h)*SS + sI)*DD;
#pragma unroll
        for (int j = 0; j < 4; ++j)
          Xh[base + j*16 + l15] = (__bf16)((x[j] - mu)*rstd*gmv[j] + btv[j]);
      }
    }
}

// ================= flash attention: dbuf + K=32 PV + MFMA row-sum + XCD swizzle =========
// 1-D grid of 512 blocks. Decode maps all 16 qb-blocks of one (b,h) to wgids with the
// same (mod 8) residue -> same XCD (wgid%8 round-robin) -> that head's 512KB K/V stays
// in ONE XCD's L2 (4 groups x 512KB = 2MB of 4MB). r16 counters showed FETCH=69.8MB =
// 2.8x the 25MB Xh (all-XCD re-fetch) and stage-drain waits at HBM-miss latency.
// Bijective: bid <-> (xcd=bid&7, qb=(bid>>3)&15, g=xcd+8*(bid>>7)); b=g>>3, h=g&7.
__global__ __launch_bounds__(512) void attn_kernel(const __bf16* Xh, const float* maskF, __bf16* AO) {
  const int bid = blockIdx.x;
  const int xcd = bid & 7;
  const int slot = bid >> 3;
  const int qb = slot & 15;
  const int g = xcd + 8*(slot >> 4);
  const int b = g >> 3, h = g & 7;

  const int t = threadIdx.x;
  const int w = t >> 6, lane = t & 63;
  const int hh = w >> 2, wq = w & 3;        // key-half, q-group
  const int l15 = lane & 15, lg = lane >> 4;

  __shared__ char smem[65536];              // [half][buf]{K 8KB, V 8KB} + overlay

  const size_t headoff = (((size_t)b*HH + h)*SS)*DD;
  const __bf16* Qg = Xh + headoff;
  const __bf16* Kg = Xh + BHSD + headoff;
  const __bf16* Vt = Xh + 2*BHSD + (((size_t)b*HH + h)*DD)*SS;   // [D][S]
  const float* qmF = maskF + (size_t)b*SS;
  const float* kmF = maskF + MM + (size_t)b*SS;

  const int q0 = qb*128 + wq*32;

  // Q fragments, pre-scaled by log2(e)/181 (exp2 domain)
  v8bf qf[2][2];
#pragma unroll
  for (int m = 0; m < 2; ++m)
#pragma unroll
    for (int kd = 0; kd < 2; ++kd) {
      v8bf r = *(const v8bf*)(Qg + (size_t)(q0 + m*16 + l15)*DD + kd*32 + lg*8);
      v8bf o;
#pragma unroll
      for (int e = 0; e < 8; ++e) o[e] = (__bf16)((float)r[e] * (SCALE_INV * LOG2E));
      qf[m][kd] = o;
    }

  v8bf onesb;
#pragma unroll
  for (int e = 0; e < 8; ++e) onesb[e] = (__bf16)1.0f;

  v4f O[2][4];
  v4f lacc[2];
  const v4f zf = {0.f,0.f,0.f,0.f};
#pragma unroll
  for (int m = 0; m < 2; ++m) {
    lacc[m] = zf;
#pragma unroll
    for (int df = 0; df < 4; ++df) O[m][df] = zf;
  }

  const int srow = lane >> 3;
  const int sc   = lane & 7;
  // K source row permutation: LDS row r <- global key sig(r).
#define SIGMA(r) (((r) & ~31) | ((((r)>>2)&3)<<3) | ((((r)>>4)&1)<<2) | ((r)&3))
#define STAGE1(BUFC, KT0)                                                                  \
  {                                                                                        \
    char* kb_ = (BUFC);                                                                    \
    char* vb_ = (BUFC) + 8192;                                                             \
    _Pragma("unroll")                                                                      \
    for (int j_ = 0; j_ < 2; ++j_) {                                                       \
      const int r0_ = wq*16 + j_*8;                                                        \
      const int r_  = r0_ + srow;                                                          \
      const int sg_ = SIGMA(r_);                                                           \
      gload_lds16(Kg + (size_t)((KT0) + sg_)*DD + ((sc ^ (r_ & 7))*8), kb_ + r0_*128);     \
      gload_lds16(Vt + (size_t)r_*SS + (KT0) + ((sc ^ (r_ & 7))*8),  vb_ + r0_*128);       \
    }                                                                                      \
  }

  char* bufA = smem + hh*32768;
  char* bufB = bufA + 16384;

  STAGE1(bufA, hh*64);
  __syncthreads();

  for (int tt = 0; tt < 16; ++tt) {
    char* cur = (tt & 1) ? bufB : bufA;
    char* nxt = (tt & 1) ? bufA : bufB;
    if (tt + 1 < 16) STAGE1(nxt, ((tt+1)*2 + hh)*64);   // hides under compute(cur)

    const int kt0 = (tt*2 + hh)*64;
    char* kb = cur;
    char* vb = cur + 8192;

    // ---- K fragments from LDS (swizzled read; rows hold sig-permuted keys) ----
    v8bf kf[4][2];
#pragma unroll
    for (int f = 0; f < 4; ++f)
#pragma unroll
      for (int kd = 0; kd < 2; ++kd) {
        const int rr = f*16 + l15;
        kf[f][kd] = *(const v8bf*)(kb + rr*128 + (((kd*4 + lg) ^ (rr & 7))*16));
      }

    // ---- S^T = K Q^T : lane q=l15; (f,rr) -> global key kt0+sig(f*16+4lg+rr) ----
    v4f st[2][4];
#pragma unroll
    for (int m = 0; m < 2; ++m)
#pragma unroll
      for (int f = 0; f < 4; ++f) st[m][f] = zf;
#pragma unroll
    for (int kd = 0; kd < 2; ++kd)
#pragma unroll
      for (int f = 0; f < 4; ++f)
#pragma unroll
        for (int m = 0; m < 2; ++m)
          st[m][f] = mfma16(kf[f][kd], qf[m][kd], st[m][f]);

    // key-mask for permuted keys: (f,rr) -> (f>>1)*32 + (f&1)*4 + 8*lg + rr (contig in rr)
    v4f km4[4];
#pragma unroll
    for (int f = 0; f < 4; ++f)
      km4[f] = *(const v4f*)(kmF + kt0 + (f >> 1)*32 + (f & 1)*4 + 8*lg);

    // ---- fixed-max softmax (native exp2) + PV at K=32 + MFMA row-sum ----
#pragma unroll
    for (int m = 0; m < 2; ++m) {
      float p[4][4];
#pragma unroll
      for (int f = 0; f < 4; ++f)
#pragma unroll
        for (int rr = 0; rr < 4; ++rr)
          p[f][rr] = fexp2(st[m][f][rr]) * km4[f][rr];
#pragma unroll
      for (int g2 = 0; g2 < 2; ++g2) {
        v8bf pa;
        pa[0] = (__bf16)p[2*g2][0];   pa[1] = (__bf16)p[2*g2][1];
        pa[2] = (__bf16)p[2*g2][2];   pa[3] = (__bf16)p[2*g2][3];
        pa[4] = (__bf16)p[2*g2+1][0]; pa[5] = (__bf16)p[2*g2+1][1];
        pa[6] = (__bf16)p[2*g2+1][2]; pa[7] = (__bf16)p[2*g2+1][3];
        lacc[m] = mfma16(pa, onesb, lacc[m]);      // rowsum: D[q][*] = sum_k p
#pragma unroll
        for (int df = 0; df < 4; ++df) {
          const int rv = df*16 + l15;
          v8bf vv = *(const v8bf*)(vb + rv*128 + (((g2*4 + lg) ^ (rv & 7))*16));
          O[m][df] = mfma16(pa, vv, O[m][df]);
        }
      }
    }
    __syncthreads();   // drains stage(next); protects cur overwrite at tt+2
  }
#undef STAGE1
#undef SIGMA

  // ---- combine halves in LDS (loop ended with barrier) ----
  // lacc layout == O layout: lane holds q = 4*lg+rr (all l15 columns identical).
  float (*Pp)[32][65] = (float (*)[32][65])smem;            // [4][32][65] = 33,280 B
  float (*Lp)[32]     = (float (*)[32])(smem + 4*32*65*4);  // +512 B
  if (hh == 1) {
#pragma unroll
    for (int m = 0; m < 2; ++m)
#pragma unroll
      for (int df = 0; df < 4; ++df)
#pragma unroll
        for (int rr = 0; rr < 4; ++rr)
          Pp[wq][m*16 + 4*lg + rr][df*16 + l15] = O[m][df][rr];
    if (l15 == 0) {
#pragma unroll
      for (int m = 0; m < 2; ++m)
#pragma unroll
        for (int rr = 0; rr < 4; ++rr)
          Lp[wq][m*16 + 4*lg + rr] = lacc[m][rr];
    }
  }
  __syncthreads();
  if (hh == 0) {
#pragma unroll
    for (int m = 0; m < 2; ++m)
#pragma unroll
      for (int df = 0; df < 4; ++df)
#pragma unroll
        for (int rr = 0; rr < 4; ++rr)
          O[m][df][rr] += Pp[wq][m*16 + 4*lg + rr][df*16 + l15];
#pragma unroll
    for (int m = 0; m < 2; ++m)
#pragma unroll
      for (int rr = 0; rr < 4; ++rr) {
        const float lr = lacc[m][rr] + Lp[wq][m*16 + 4*lg + rr];
        const int qrow = q0 + m*16 + 4*lg + rr;
        const float scl = qmF[qrow] / fmaxf(lr, 1e-30f);
#pragma unroll
        for (int df = 0; df < 4; ++df)
          AO[(size_t)(b*SS + qrow)*EE + h*DD + df*16 + l15] = (__bf16)(O[m][df][rr] * scl);
      }
  }
}

// ================= output GEMM: out = (AO @ Wo^T + bo) * qmask =================
// (unchanged from round 11)
__global__ __launch_bounds__(256) void gemm_out(const __bf16* AO, const __bf16* Wb,
                                                const float* bo, const float* maskF, float* out) {
  const int m0 = blockIdx.x * 128;
  const int n0 = blockIdx.y * 128;
  const __bf16* A = AO;
  const __bf16* W = Wb + (size_t)3*EE*EE;   // Wo

  __shared__ char smem[32768];

  const int t = threadIdx.x;
  const int lane = t & 63, w = t >> 6;
  const int wm = w >> 1, wn = w & 1;
  const int l15 = lane & 15, lg = lane >> 4;

  v4f acc[4][4];
  const v4f zf = {0.f,0.f,0.f,0.f};
#pragma unroll
  for (int i = 0; i < 4; ++i)
#pragma unroll
    for (int j = 0; j < 4; ++j) acc[i][j] = zf;

  const int sr0 = (w*64 + lane) >> 2;
  const int sct = (w*64 + lane) & 3;
#define STAGE_PL(BUF, KT)                                                                 \
  {                                                                                       \
    char* ab_ = (BUF);                                                                    \
    char* bb_ = (BUF) + 8192;                                                             \
    _Pragma("unroll")                                                                     \
    for (int j_ = 0; j_ < 2; ++j_) {                                                      \
      const int r_ = sr0 + j_*64;                                                         \
      const int c_ = sct ^ (r_ & 3);                                                      \
      gload_lds16(A + (size_t)(m0 + r_)*EE + (KT) + c_*8, ab_ + j_*4096 + w*1024);        \
      gload_lds16(W + (size_t)(n0 + r_)*EE + (KT) + c_*8, bb_ + j_*4096 + w*1024);        \
    }                                                                                     \
  }

  char* buf0 = smem;
  char* buf1 = smem + 16384;

  STAGE_PL(buf0, 0);
  __syncthreads();

  int cur = 0;
  for (int kt = 0; kt < EE; kt += 32) {
    char* cb = cur ? buf1 : buf0;
    char* nb = cur ? buf0 : buf1;
    if (kt + 32 < EE) STAGE_PL(nb, kt + 32);

    const char* As = cb;
    const char* Bs = cb + 8192;
    v8bf afr[4], bfr[4];
#pragma unroll
    for (int i = 0; i < 4; ++i) {
      const int ra = wm*64 + i*16 + l15;
      afr[i] = *(const v8bf*)(As + ra*64 + ((16*lg) ^ ((ra & 3) << 4)));
      const int rb = wn*64 + i*16 + l15;
      bfr[i] = *(const v8bf*)(Bs + rb*64 + ((16*lg) ^ ((rb & 3) << 4)));
    }
#pragma unroll
    for (int i = 0; i < 4; ++i)
#pragma unroll
      for (int j = 0; j < 4; ++j)
        acc[i][j] = mfma16(afr[i], bfr[j], acc[i][j]);
    __syncthreads();
    cur ^= 1;
  }
#undef STAGE_PL

  float bsv[4]; int ncol[4];
#pragma unroll
  for (int j = 0; j < 4; ++j) {
    ncol[j] = n0 + wn*64 + j*16 + l15;
    bsv[j] = bo[ncol[j]];
  }
#pragma unroll
  for (int i = 0; i < 4; ++i)
#pragma unroll
    for (int rr = 0; rr < 4; ++rr) {
      const int row = m0 + wm*64 + i*16 + 4*lg + rr;
      const float mv = maskF[row];   // query mask
#pragma unroll
      for (int j = 0; j < 4; ++j)
        out[(size_t)row*EE + ncol[j]] = (acc[i][j][rr] + bsv[j]) * mv;
    }
}

// ================= launcher =================
extern "C" void kernel_launch(void* const* d_in, const int* in_sizes, int n_in,
                              void* d_out, int out_size, void* d_ws, size_t ws_size,
                              hipStream_t stream) {
  const float* q  = (const float*)d_in[0];
  const float* k  = (const float*)d_in[1];
  const float* v  = (const float*)d_in[2];
  const float* Wq = (const float*)d_in[3];
  const float* bq = (const float*)d_in[4];
  const float* Wk = (const float*)d_in[5];
  const float* bk = (const float*)d_in[6];
  const float* Wv = (const float*)d_in[7];
  const float* bv = (const float*)d_in[8];
  const float* Wo = (const float*)d_in[9];
  const float* bo = (const float*)d_in[10];
  const float* gq = (const float*)d_in[11];
  const float* betaq = (const float*)d_in[12];
  const float* gk = (const float*)d_in[13];
  const float* betak = (const float*)d_in[14];
  const float* gv = (const float*)d_in[15];
  const float* betav = (const float*)d_in[16];

  char* ws = (char*)d_ws;
  __bf16* Xb = (__bf16*)(ws + oXb);
  __bf16* Wb = (__bf16*)(ws + oWb);
  __bf16* Xh = (__bf16*)(ws + oXh);
  __bf16* AO = (__bf16*)(ws + oAO);
  float*  maskF = (float*)(ws + oMk);

  mask_kernel<<<dim3(96), dim3(256), 0, stream>>>(d_in[17], d_in[18], d_in[19], maskF);
  convert_kernel<<<dim3(13312), dim3(256), 0, stream>>>(q, k, v, Wq, Wk, Wv, Wo, Xb, Wb);
  gemm_proj_ln<<<dim3(64, 4, 3), dim3(256), 0, stream>>>(Xb, Wb, bq, bk, bv,
                                                         gq, betaq, gk, betak, gv, betav,
                                                         maskF, Xh);
  attn_kernel<<<dim3(512), dim3(512), 0, stream>>>(Xh, maskF, AO);
  gemm_out<<<dim3(64, 4, 1), dim3(256), 0, stream>>>(AO, Wb, bo, maskF, (float*)d_out);
}

// Round 21
// 108.578 us; speedup vs baseline: 1.1488x; 1.0583x over previous
//
#include <hip/hip_runtime.h>
#include <cstdint>
#include <cstddef>

// ---------------- problem constants ----------------
#define BB 4
#define SS 2048
#define EE 512
#define HH 8
#define DD 64
#define MM (BB*SS)                       // 8192 token rows
#define BHSD ((size_t)BB*HH*SS*DD)       // 4194304 elements per q/k/v head tensor

static constexpr float SCALE_INV = 1.0f / 181.0f;   // SCALE = float(512 // 8**0.5) = 181.0
static constexpr float LOG2E = 1.4426950408889634f;
static constexpr float LN_EPS = 1e-5f;

typedef float  v4f  __attribute__((ext_vector_type(4)));
typedef __bf16 v8bf __attribute__((ext_vector_type(8)));
typedef __bf16 v4bf __attribute__((ext_vector_type(4)));
typedef short  s4   __attribute__((ext_vector_type(4)));

static __device__ __forceinline__ v4f mfma16(v8bf a, v8bf b, v4f c) {
  return __builtin_amdgcn_mfma_f32_16x16x32_bf16(a, b, c, 0, 0, 0);
}

// native 2^x (v_exp_f32); libm exp2f regressed (r15: denormal path).
static __device__ __forceinline__ float fexp2(float x) {
#if __has_builtin(__builtin_amdgcn_exp2f)
  return __builtin_amdgcn_exp2f(x);
#else
  return __expf(x * 0.6931471805599453f);
#endif
}

// async global->LDS, 16B per lane; LDS dest = wave-uniform base + lane*16 (HW rule).
typedef const void __attribute__((address_space(1))) gas_void;
typedef void __attribute__((address_space(3))) las_void;
static __device__ __forceinline__ void gload_lds16(const void* g, void* l) {
  __builtin_amdgcn_global_load_lds((gas_void*)g, (las_void*)l, 16, 0, 0);
}

// ---------------- workspace layout (bytes) ----------------
// Wb  bf16 [4][E][E]; Xh bf16 q/k/vT; AO bf16 [M][E]; maskF f32 [3][M]
static constexpr size_t oWb = 0;
static constexpr size_t oXh = oWb + (size_t)4*EE*EE*2;
static constexpr size_t oAO = oXh + (size_t)3*MM*EE*2;
static constexpr size_t oMk = oAO + (size_t)MM*EE*2;

// ================= mask canonicalization (parallel) =================
__global__ void mask_kernel(const void* qm, const void* km, const void* vm, float* maskF) {
  __shared__ int s_n01, s_nF;
  const int t = threadIdx.x;
  if (t == 0) { s_n01 = 0; s_nF = 0; }
  __syncthreads();
  int n01 = 0, nF = 0;
  const unsigned* wq = (const unsigned*)qm;
  for (int i = t; i < 2048; i += 256) {
    const unsigned u = wq[i];
    if (u != 0u && u != 1u) n01 = 1;
    if (u != 0u && u != 0x3F800000u) nF = 1;
  }
  if (n01) atomicOr(&s_n01, 1);
  if (nF)  atomicOr(&s_nF, 1);
  __syncthreads();
  const int mode = (!s_n01) ? 0 : (!s_nF) ? 1 : 2;   // 0=i32, 1=f32, 2=u8
  const int gidx = blockIdx.x * 256 + t;
  const int m = gidx / MM, i = gidx % MM;
  const void* p = (m == 0) ? qm : (m == 1) ? km : vm;
  int v;
  if (mode == 0)      v = (((const int*)p)[i] != 0);
  else if (mode == 1) v = (((const unsigned*)p)[i] != 0u);
  else                v = (((const unsigned char*)p)[i] != 0);
  maskF[m*MM + i] = v ? 1.0f : 0.0f;
}

// ================= fp32 -> bf16 convert (WEIGHTS ONLY now) =================
__global__ void convert_kernel(const float* Wq, const float* Wk, const float* Wv, const float* Wo,
                               __bf16* Wb) {
  const long j = (long)blockIdx.x * 256 + threadIdx.x;   // float4 units, 262144 total
  const long per = (long)EE*EE/4;
  const long mat = j / per, off = j % per;
  const float* src = (mat == 0) ? Wq : (mat == 1) ? Wk : (mat == 2) ? Wv : Wo;
  v4f val = ((const v4f*)src)[off];
  v4bf o; o[0]=(__bf16)val[0]; o[1]=(__bf16)val[1]; o[2]=(__bf16)val[2]; o[3]=(__bf16)val[3];
  ((v4bf*)Wb)[j] = o;
}

// ===== projection GEMM (fp32 A staged directly) + bias + mask + per-head LN, fused =====
// A (q/k/v input) is staged as RAW FP32 via global_load_lds (16B = 4 floats) and
// converted to bf16 in the LDS->register path -- deletes the 50MB Xb round-trip.
// A-tile: 128 rows x 32 k x 4B = 16KB/buf, 128B rows = 8 chunks, c^(r&7) involution
// on source+read. B (weights) bf16, unchanged 64B-row c^(r&3). dbuf = 2x24KB = 48KB.
// mat 2 (v) written TRANSPOSED [B][H][D][S].
__global__ __launch_bounds__(256) void gemm_proj_ln(const float* Aq, const float* Ak, const float* Av,
                                                    const __bf16* Wb,
                                                    const float* bq, const float* bk, const float* bv,
                                                    const float* gq, const float* betaq,
                                                    const float* gk, const float* betak,
                                                    const float* gv, const float* betav,
                                                    const float* maskF, __bf16* Xh) {
  const int m0  = blockIdx.x * 128;
  const int n0  = blockIdx.y * 128;
  const int mat = blockIdx.z;
  const float* A = (mat == 0) ? Aq : (mat == 1) ? Ak : Av;
  const __bf16* W = Wb + (size_t)mat*EE*EE;
  const float* bias = (mat == 0) ? bq : (mat == 1) ? bk : bv;
  const float* gam  = (mat == 0) ? gq : (mat == 1) ? gk : gv;
  const float* bet  = (mat == 0) ? betaq : (mat == 1) ? betak : betav;

  __shared__ char smem[49152];   // [buf][A_f32 16KB | B_bf16 8KB]

  const int t = threadIdx.x;
  const int lane = t & 63, w = t >> 6;
  const int wm = w >> 1, wn = w & 1;
  const int l15 = lane & 15, lg = lane >> 4;

  v4f acc[4][4];
  const v4f zf = {0.f, 0.f, 0.f, 0.f};
#pragma unroll
  for (int i = 0; i < 4; ++i)
#pragma unroll
    for (int j = 0; j < 4; ++j) acc[i][j] = zf;

  // B staging geometry (bf16, 64B rows, 4 chunks): flat = j*256 + t
  const int sr0 = (w*64 + lane) >> 2;
  const int sct = (w*64 + lane) & 3;
#define STAGE_PL(BUF, KT)                                                                 \
  {                                                                                       \
    char* ab_ = (BUF);                                                                    \
    char* bb_ = (BUF) + 16384;                                                            \
    _Pragma("unroll")                                                                     \
    for (int j_ = 0; j_ < 4; ++j_) {        /* A fp32: 4 x 16B per thread */              \
      const int fl_ = j_*256 + w*64 + lane;                                               \
      const int r_  = fl_ >> 3;                                                           \
      const int s_  = fl_ & 7;                                                            \
      const int c_  = s_ ^ (r_ & 7);                                                      \
      gload_lds16(A + (size_t)(m0 + r_)*EE + (KT) + c_*4, ab_ + (j_*4 + w)*1024);         \
    }                                                                                     \
    _Pragma("unroll")                                                                     \
    for (int j_ = 0; j_ < 2; ++j_) {        /* B bf16: 2 x 16B per thread */              \
      const int r_ = sr0 + j_*64;                                                         \
      const int c_ = sct ^ (r_ & 3);                                                      \
      gload_lds16(W + (size_t)(n0 + r_)*EE + (KT) + c_*8, bb_ + j_*4096 + w*1024);        \
    }                                                                                     \
  }

  char* buf0 = smem;
  char* buf1 = smem + 24576;

  STAGE_PL(buf0, 0);
  __syncthreads();

  int cur = 0;
  for (int kt = 0; kt < EE; kt += 32) {
    char* cb = cur ? buf1 : buf0;
    char* nb = cur ? buf0 : buf1;
    if (kt + 32 < EE) STAGE_PL(nb, kt + 32);

    const char* As = cb;           // fp32 [128][128B]
    const char* Bs = cb + 16384;   // bf16 [128][64B]
    v8bf afr[4], bfr[4];
#pragma unroll
    for (int i = 0; i < 4; ++i) {
      const int ra = wm*64 + i*16 + l15;
      const int c0 = (2*lg) ^ (ra & 7);
      const int c1 = (2*lg + 1) ^ (ra & 7);
      v4f f0 = *(const v4f*)(As + ra*128 + c0*16);
      v4f f1 = *(const v4f*)(As + ra*128 + c1*16);
      v8bf a;
      a[0]=(__bf16)f0[0]; a[1]=(__bf16)f0[1]; a[2]=(__bf16)f0[2]; a[3]=(__bf16)f0[3];
      a[4]=(__bf16)f1[0]; a[5]=(__bf16)f1[1]; a[6]=(__bf16)f1[2]; a[7]=(__bf16)f1[3];
      afr[i] = a;
      const int rb = wn*64 + i*16 + l15;
      bfr[i] = *(const v8bf*)(Bs + rb*64 + ((16*lg) ^ ((rb & 3) << 4)));
    }
#pragma unroll
    for (int i = 0; i < 4; ++i)
#pragma unroll
      for (int j = 0; j < 4; ++j)
        acc[i][j] = mfma16(afr[i], bfr[j], acc[i][j]);
    __syncthreads();
    cur ^= 1;
  }
#undef STAGE_PL

  const int nbase = n0 + wn*64;          // 64-aligned => one head
  const int h = nbase >> 6;
  float bsv[4], gmv[4], btv[4];
#pragma unroll
  for (int j = 0; j < 4; ++j) {
    const int d = j*16 + l15;
    bsv[j] = bias[nbase + d];
    gmv[j] = gam[d];
    btv[j] = bet[d];
  }
#pragma unroll
  for (int i = 0; i < 4; ++i)
#pragma unroll
    for (int rr = 0; rr < 4; ++rr) {
      const int row = m0 + wm*64 + i*16 + 4*lg + rr;
      const float mv = maskF[mat*MM + row];
      float x[4];
      float s = 0.f, s2 = 0.f;
#pragma unroll
      for (int j = 0; j < 4; ++j) {
        x[j] = (acc[i][j][rr] + bsv[j]) * mv;
        s += x[j]; s2 += x[j]*x[j];
      }
      s  += __shfl_xor(s, 1, 64);  s  += __shfl_xor(s, 2, 64);
      s  += __shfl_xor(s, 4, 64);  s  += __shfl_xor(s, 8, 64);
      s2 += __shfl_xor(s2, 1, 64); s2 += __shfl_xor(s2, 2, 64);
      s2 += __shfl_xor(s2, 4, 64); s2 += __shfl_xor(s2, 8, 64);
      const float mu  = s * (1.0f/64.0f);
      const float var = s2 * (1.0f/64.0f) - mu*mu;
      const float rstd = rsqrtf(var + LN_EPS);
      const int bidx = row >> 11, sI = row & 2047;
      if (mat == 2) {
        const size_t vbase = 2*BHSD + (((size_t)bidx*HH + h)*DD)*SS;
#pragma unroll
        for (int j = 0; j < 4; ++j)
          Xh[vbase + (size_t)(j*16 + l15)*SS + sI] = (__bf16)((x[j] - mu)*rstd*gmv[j] + btv[j]);
      } else {
        const size_t base = (size_t)mat*BHSD + (((size_t)bidx*HH + h)*SS + sI)*DD;
#pragma unroll
        for (int j = 0; j < 4; ++j)
          Xh[base + j*16 + l15] = (__bf16)((x[j] - mu)*rstd*gmv[j] + btv[j]);
      }
    }
}

// ================= flash attention: dbuf + K=32 PV + MFMA row-sum + XCD swizzle =========
// (unchanged from round 18 -- passing at 55.3us, FETCH 12.6MB)
__global__ __launch_bounds__(512) void attn_kernel(const __bf16* Xh, const float* maskF, __bf16* AO) {
  const int bid = blockIdx.x;
  const int xcd = bid & 7;
  const int slot = bid >> 3;
  const int qb = slot & 15;
  const int g = xcd + 8*(slot >> 4);
  const int b = g >> 3, h = g & 7;

  const int t = threadIdx.x;
  const int w = t >> 6, lane = t & 63;
  const int hh = w >> 2, wq = w & 3;        // key-half, q-group
  const int l15 = lane & 15, lg = lane >> 4;

  __shared__ char smem[65536];              // [half][buf]{K 8KB, V 8KB} + overlay

  const size_t headoff = (((size_t)b*HH + h)*SS)*DD;
  const __bf16* Qg = Xh + headoff;
  const __bf16* Kg = Xh + BHSD + headoff;
  const __bf16* Vt = Xh + 2*BHSD + (((size_t)b*HH + h)*DD)*SS;   // [D][S]
  const float* qmF = maskF + (size_t)b*SS;
  const float* kmF = maskF + MM + (size_t)b*SS;

  const int q0 = qb*128 + wq*32;

  // Q fragments, pre-scaled by log2(e)/181 (exp2 domain)
  v8bf qf[2][2];
#pragma unroll
  for (int m = 0; m < 2; ++m)
#pragma unroll
    for (int kd = 0; kd < 2; ++kd) {
      v8bf r = *(const v8bf*)(Qg + (size_t)(q0 + m*16 + l15)*DD + kd*32 + lg*8);
      v8bf o;
#pragma unroll
      for (int e = 0; e < 8; ++e) o[e] = (__bf16)((float)r[e] * (SCALE_INV * LOG2E));
      qf[m][kd] = o;
    }

  v8bf onesb;
#pragma unroll
  for (int e = 0; e < 8; ++e) onesb[e] = (__bf16)1.0f;

  v4f O[2][4];
  v4f lacc[2];
  const v4f zf = {0.f,0.f,0.f,0.f};
#pragma unroll
  for (int m = 0; m < 2; ++m) {
    lacc[m] = zf;
#pragma unroll
    for (int df = 0; df < 4; ++df) O[m][df] = zf;
  }

  const int srow = lane >> 3;
  const int sc   = lane & 7;
  // K source row permutation: LDS row r <- global key sig(r).
#define SIGMA(r) (((r) & ~31) | ((((r)>>2)&3)<<3) | ((((r)>>4)&1)<<2) | ((r)&3))
#define STAGE1(BUFC, KT0)                                                                  \
  {                                                                                        \
    char* kb_ = (BUFC);                                                                    \
    char* vb_ = (BUFC) + 8192;                                                             \
    _Pragma("unroll")                                                                      \
    for (int j_ = 0; j_ < 2; ++j_) {                                                       \
      const int r0_ = wq*16 + j_*8;                                                        \
      const int r_  = r0_ + srow;                                                          \
      const int sg_ = SIGMA(r_);                                                           \
      gload_lds16(Kg + (size_t)((KT0) + sg_)*DD + ((sc ^ (r_ & 7))*8), kb_ + r0_*128);     \
      gload_lds16(Vt + (size_t)r_*SS + (KT0) + ((sc ^ (r_ & 7))*8),  vb_ + r0_*128);       \
    }                                                                                      \
  }

  char* bufA = smem + hh*32768;
  char* bufB = bufA + 16384;

  STAGE1(bufA, hh*64);
  __syncthreads();

  for (int tt = 0; tt < 16; ++tt) {
    char* cur = (tt & 1) ? bufB : bufA;
    char* nxt = (tt & 1) ? bufA : bufB;
    if (tt + 1 < 16) STAGE1(nxt, ((tt+1)*2 + hh)*64);   // hides under compute(cur)

    const int kt0 = (tt*2 + hh)*64;
    char* kb = cur;
    char* vb = cur + 8192;

    // ---- K fragments from LDS (swizzled read; rows hold sig-permuted keys) ----
    v8bf kf[4][2];
#pragma unroll
    for (int f = 0; f < 4; ++f)
#pragma unroll
      for (int kd = 0; kd < 2; ++kd) {
        const int rr = f*16 + l15;
        kf[f][kd] = *(const v8bf*)(kb + rr*128 + (((kd*4 + lg) ^ (rr & 7))*16));
      }

    // ---- S^T = K Q^T : lane q=l15; (f,rr) -> global key kt0+sig(f*16+4lg+rr) ----
    v4f st[2][4];
#pragma unroll
    for (int m = 0; m < 2; ++m)
#pragma unroll
      for (int f = 0; f < 4; ++f) st[m][f] = zf;
#pragma unroll
    for (int kd = 0; kd < 2; ++kd)
#pragma unroll
      for (int f = 0; f < 4; ++f)
#pragma unroll
        for (int m = 0; m < 2; ++m)
          st[m][f] = mfma16(kf[f][kd], qf[m][kd], st[m][f]);

    // key-mask for permuted keys: (f,rr) -> (f>>1)*32 + (f&1)*4 + 8*lg + rr (contig in rr)
    v4f km4[4];
#pragma unroll
    for (int f = 0; f < 4; ++f)
      km4[f] = *(const v4f*)(kmF + kt0 + (f >> 1)*32 + (f & 1)*4 + 8*lg);

    // ---- fixed-max softmax (native exp2) + PV at K=32 + MFMA row-sum ----
#pragma unroll
    for (int m = 0; m < 2; ++m) {
      float p[4][4];
#pragma unroll
      for (int f = 0; f < 4; ++f)
#pragma unroll
        for (int rr = 0; rr < 4; ++rr)
          p[f][rr] = fexp2(st[m][f][rr]) * km4[f][rr];
#pragma unroll
      for (int g2 = 0; g2 < 2; ++g2) {
        v8bf pa;
        pa[0] = (__bf16)p[2*g2][0];   pa[1] = (__bf16)p[2*g2][1];
        pa[2] = (__bf16)p[2*g2][2];   pa[3] = (__bf16)p[2*g2][3];
        pa[4] = (__bf16)p[2*g2+1][0]; pa[5] = (__bf16)p[2*g2+1][1];
        pa[6] = (__bf16)p[2*g2+1][2]; pa[7] = (__bf16)p[2*g2+1][3];
        lacc[m] = mfma16(pa, onesb, lacc[m]);      // rowsum: D[q][*] = sum_k p
#pragma unroll
        for (int df = 0; df < 4; ++df) {
          const int rv = df*16 + l15;
          v8bf vv = *(const v8bf*)(vb + rv*128 + (((g2*4 + lg) ^ (rv & 7))*16));
          O[m][df] = mfma16(pa, vv, O[m][df]);
        }
      }
    }
    __syncthreads();   // drains stage(next); protects cur overwrite at tt+2
  }
#undef STAGE1
#undef SIGMA

  // ---- combine halves in LDS (loop ended with barrier) ----
  // lacc layout == O layout: lane holds q = 4*lg+rr (all l15 columns identical).
  float (*Pp)[32][65] = (float (*)[32][65])smem;            // [4][32][65] = 33,280 B
  float (*Lp)[32]     = (float (*)[32])(smem + 4*32*65*4);  // +512 B
  if (hh == 1) {
#pragma unroll
    for (int m = 0; m < 2; ++m)
#pragma unroll
      for (int df = 0; df < 4; ++df)
#pragma unroll
        for (int rr = 0; rr < 4; ++rr)
          Pp[wq][m*16 + 4*lg + rr][df*16 + l15] = O[m][df][rr];
    if (l15 == 0) {
#pragma unroll
      for (int m = 0; m < 2; ++m)
#pragma unroll
        for (int rr = 0; rr < 4; ++rr)
          Lp[wq][m*16 + 4*lg + rr] = lacc[m][rr];
    }
  }
  __syncthreads();
  if (hh == 0) {
#pragma unroll
    for (int m = 0; m < 2; ++m)
#pragma unroll
      for (int df = 0; df < 4; ++df)
#pragma unroll
        for (int rr = 0; rr < 4; ++rr)
          O[m][df][rr] += Pp[wq][m*16 + 4*lg + rr][df*16 + l15];
#pragma unroll
    for (int m = 0; m < 2; ++m)
#pragma unroll
      for (int rr = 0; rr < 4; ++rr) {
        const float lr = lacc[m][rr] + Lp[wq][m*16 + 4*lg + rr];
        const int qrow = q0 + m*16 + 4*lg + rr;
        const float scl = qmF[qrow] / fmaxf(lr, 1e-30f);
#pragma unroll
        for (int df = 0; df < 4; ++df)
          AO[(size_t)(b*SS + qrow)*EE + h*DD + df*16 + l15] = (__bf16)(O[m][df][rr] * scl);
      }
  }
}

// ================= output GEMM: out = (AO @ Wo^T + bo) * qmask =================
// (unchanged from round 11)
__global__ __launch_bounds__(256) void gemm_out(const __bf16* AO, const __bf16* Wb,
                                                const float* bo, const float* maskF, float* out) {
  const int m0 = blockIdx.x * 128;
  const int n0 = blockIdx.y * 128;
  const __bf16* A = AO;
  const __bf16* W = Wb + (size_t)3*EE*EE;   // Wo

  __shared__ char smem[32768];

  const int t = threadIdx.x;
  const int lane = t & 63, w = t >> 6;
  const int wm = w >> 1, wn = w & 1;
  const int l15 = lane & 15, lg = lane >> 4;

  v4f acc[4][4];
  const v4f zf = {0.f,0.f,0.f,0.f};
#pragma unroll
  for (int i = 0; i < 4; ++i)
#pragma unroll
    for (int j = 0; j < 4; ++j) acc[i][j] = zf;

  const int sr0 = (w*64 + lane) >> 2;
  const int sct = (w*64 + lane) & 3;
#define STAGE_PL(BUF, KT)                                                                 \
  {                                                                                       \
    char* ab_ = (BUF);                                                                    \
    char* bb_ = (BUF) + 8192;                                                             \
    _Pragma("unroll")                                                                     \
    for (int j_ = 0; j_ < 2; ++j_) {                                                      \
      const int r_ = sr0 + j_*64;                                                         \
      const int c_ = sct ^ (r_ & 3);                                                      \
      gload_lds16(A + (size_t)(m0 + r_)*EE + (KT) + c_*8, ab_ + j_*4096 + w*1024);        \
      gload_lds16(W + (size_t)(n0 + r_)*EE + (KT) + c_*8, bb_ + j_*4096 + w*1024);        \
    }                                                                                     \
  }

  char* buf0 = smem;
  char* buf1 = smem + 16384;

  STAGE_PL(buf0, 0);
  __syncthreads();

  int cur = 0;
  for (int kt = 0; kt < EE; kt += 32) {
    char* cb = cur ? buf1 : buf0;
    char* nb = cur ? buf0 : buf1;
    if (kt + 32 < EE) STAGE_PL(nb, kt + 32);

    const char* As = cb;
    const char* Bs = cb + 8192;
    v8bf afr[4], bfr[4];
#pragma unroll
    for (int i = 0; i < 4; ++i) {
      const int ra = wm*64 + i*16 + l15;
      afr[i] = *(const v8bf*)(As + ra*64 + ((16*lg) ^ ((ra & 3) << 4)));
      const int rb = wn*64 + i*16 + l15;
      bfr[i] = *(const v8bf*)(Bs + rb*64 + ((16*lg) ^ ((rb & 3) << 4)));
    }
#pragma unroll
    for (int i = 0; i < 4; ++i)
#pragma unroll
      for (int j = 0; j < 4; ++j)
        acc[i][j] = mfma16(afr[i], bfr[j], acc[i][j]);
    __syncthreads();
    cur ^= 1;
  }
#undef STAGE_PL

  float bsv[4]; int ncol[4];
#pragma unroll
  for (int j = 0; j < 4; ++j) {
    ncol[j] = n0 + wn*64 + j*16 + l15;
    bsv[j] = bo[ncol[j]];
  }
#pragma unroll
  for (int i = 0; i < 4; ++i)
#pragma unroll
    for (int rr = 0; rr < 4; ++rr) {
      const int row = m0 + wm*64 + i*16 + 4*lg + rr;
      const float mv = maskF[row];   // query mask
#pragma unroll
      for (int j = 0; j < 4; ++j)
        out[(size_t)row*EE + ncol[j]] = (acc[i][j][rr] + bsv[j]) * mv;
    }
}

// ================= launcher =================
extern "C" void kernel_launch(void* const* d_in, const int* in_sizes, int n_in,
                              void* d_out, int out_size, void* d_ws, size_t ws_size,
                              hipStream_t stream) {
  const float* q  = (const float*)d_in[0];
  const float* k  = (const float*)d_in[1];
  const float* v  = (const float*)d_in[2];
  const float* Wq = (const float*)d_in[3];
  const float* bq = (const float*)d_in[4];
  const float* Wk = (const float*)d_in[5];
  const float* bk = (const float*)d_in[6];
  const float* Wv = (const float*)d_in[7];
  const float* bv = (const float*)d_in[8];
  const float* Wo = (const float*)d_in[9];
  const float* bo = (const float*)d_in[10];
  const float* gq = (const float*)d_in[11];
  const float* betaq = (const float*)d_in[12];
  const float* gk = (const float*)d_in[13];
  const float* betak = (const float*)d_in[14];
  const float* gv = (const float*)d_in[15];
  const float* betav = (const float*)d_in[16];

  char* ws = (char*)d_ws;
  __bf16* Wb = (__bf16*)(ws + oWb);
  __bf16* Xh = (__bf16*)(ws + oXh);
  __bf16* AO = (__bf16*)(ws + oAO);
  float*  maskF = (float*)(ws + oMk);

  mask_kernel<<<dim3(96), dim3(256), 0, stream>>>(d_in[17], d_in[18], d_in[19], maskF);
  convert_kernel<<<dim3(1024), dim3(256), 0, stream>>>(Wq, Wk, Wv, Wo, Wb);
  gemm_proj_ln<<<dim3(64, 4, 3), dim3(256), 0, stream>>>(q, k, v, Wb, bq, bk, bv,
                                                         gq, betaq, gk, betak, gv, betav,
                                                         maskF, Xh);
  attn_kernel<<<dim3(512), dim3(512), 0, stream>>>(Xh, maskF, AO);
  gemm_out<<<dim3(64, 4, 1), dim3(256), 0, stream>>>(AO, Wb, bo, maskF, (float*)d_out);
}

// Round 22
// 107.363 us; speedup vs baseline: 1.1618x; 1.0113x over previous
//
#include <hip/hip_runtime.h>
#include <cstdint>
#include <cstddef>

// ---------------- problem constants ----------------
#define BB 4
#define SS 2048
#define EE 512
#define HH 8
#define DD 64
#define MM (BB*SS)                       // 8192 token rows
#define BHSD ((size_t)BB*HH*SS*DD)       // 4194304 elements per q/k/v head tensor

static constexpr float SCALE_INV = 1.0f / 181.0f;   // SCALE = float(512 // 8**0.5) = 181.0
static constexpr float LOG2E = 1.4426950408889634f;
static constexpr float LN_EPS = 1e-5f;

typedef float  v4f  __attribute__((ext_vector_type(4)));
typedef __bf16 v8bf __attribute__((ext_vector_type(8)));
typedef __bf16 v4bf __attribute__((ext_vector_type(4)));
typedef short  s4   __attribute__((ext_vector_type(4)));

static __device__ __forceinline__ v4f mfma16(v8bf a, v8bf b, v4f c) {
  return __builtin_amdgcn_mfma_f32_16x16x32_bf16(a, b, c, 0, 0, 0);
}

// native 2^x (v_exp_f32); libm exp2f regressed (r15: denormal path).
static __device__ __forceinline__ float fexp2(float x) {
#if __has_builtin(__builtin_amdgcn_exp2f)
  return __builtin_amdgcn_exp2f(x);
#else
  return __expf(x * 0.6931471805599453f);
#endif
}

// async global->LDS, 16B per lane; LDS dest = wave-uniform base + lane*16 (HW rule).
typedef const void __attribute__((address_space(1))) gas_void;
typedef void __attribute__((address_space(3))) las_void;
static __device__ __forceinline__ void gload_lds16(const void* g, void* l) {
  __builtin_amdgcn_global_load_lds((gas_void*)g, (las_void*)l, 16, 0, 0);
}

// ---------------- workspace layout (bytes) ----------------
// Wb  bf16 [4][E][E]; Xh bf16 q/k/vT; AO bf16 [M][E]; maskF f32 [3][M]
static constexpr size_t oWb = 0;
static constexpr size_t oXh = oWb + (size_t)4*EE*EE*2;
static constexpr size_t oAO = oXh + (size_t)3*MM*EE*2;
static constexpr size_t oMk = oAO + (size_t)MM*EE*2;

// ================= mask canonicalization (parallel) =================
__global__ void mask_kernel(const void* qm, const void* km, const void* vm, float* maskF) {
  __shared__ int s_n01, s_nF;
  const int t = threadIdx.x;
  if (t == 0) { s_n01 = 0; s_nF = 0; }
  __syncthreads();
  int n01 = 0, nF = 0;
  const unsigned* wq = (const unsigned*)qm;
  for (int i = t; i < 2048; i += 256) {
    const unsigned u = wq[i];
    if (u != 0u && u != 1u) n01 = 1;
    if (u != 0u && u != 0x3F800000u) nF = 1;
  }
  if (n01) atomicOr(&s_n01, 1);
  if (nF)  atomicOr(&s_nF, 1);
  __syncthreads();
  const int mode = (!s_n01) ? 0 : (!s_nF) ? 1 : 2;   // 0=i32, 1=f32, 2=u8
  const int gidx = blockIdx.x * 256 + t;
  const int m = gidx / MM, i = gidx % MM;
  const void* p = (m == 0) ? qm : (m == 1) ? km : vm;
  int v;
  if (mode == 0)      v = (((const int*)p)[i] != 0);
  else if (mode == 1) v = (((const unsigned*)p)[i] != 0u);
  else                v = (((const unsigned char*)p)[i] != 0);
  maskF[m*MM + i] = v ? 1.0f : 0.0f;
}

// ================= fp32 -> bf16 convert (weights only) =================
__global__ void convert_kernel(const float* Wq, const float* Wk, const float* Wv, const float* Wo,
                               __bf16* Wb) {
  const long j = (long)blockIdx.x * 256 + threadIdx.x;   // float4 units, 262144 total
  const long per = (long)EE*EE/4;
  const long mat = j / per, off = j % per;
  const float* src = (mat == 0) ? Wq : (mat == 1) ? Wk : (mat == 2) ? Wv : Wo;
  v4f val = ((const v4f*)src)[off];
  v4bf o; o[0]=(__bf16)val[0]; o[1]=(__bf16)val[1]; o[2]=(__bf16)val[2]; o[3]=(__bf16)val[3];
  ((v4bf*)Wb)[j] = o;
}

// ===== projection GEMM (fp32 A staged directly) + bias + mask + per-head LN, fused =====
// (unchanged from round 21 -- passing)
__global__ __launch_bounds__(256) void gemm_proj_ln(const float* Aq, const float* Ak, const float* Av,
                                                    const __bf16* Wb,
                                                    const float* bq, const float* bk, const float* bv,
                                                    const float* gq, const float* betaq,
                                                    const float* gk, const float* betak,
                                                    const float* gv, const float* betav,
                                                    const float* maskF, __bf16* Xh) {
  const int m0  = blockIdx.x * 128;
  const int n0  = blockIdx.y * 128;
  const int mat = blockIdx.z;
  const float* A = (mat == 0) ? Aq : (mat == 1) ? Ak : Av;
  const __bf16* W = Wb + (size_t)mat*EE*EE;
  const float* bias = (mat == 0) ? bq : (mat == 1) ? bk : bv;
  const float* gam  = (mat == 0) ? gq : (mat == 1) ? gk : gv;
  const float* bet  = (mat == 0) ? betaq : (mat == 1) ? betak : betav;

  __shared__ char smem[49152];   // [buf][A_f32 16KB | B_bf16 8KB]

  const int t = threadIdx.x;
  const int lane = t & 63, w = t >> 6;
  const int wm = w >> 1, wn = w & 1;
  const int l15 = lane & 15, lg = lane >> 4;

  v4f acc[4][4];
  const v4f zf = {0.f, 0.f, 0.f, 0.f};
#pragma unroll
  for (int i = 0; i < 4; ++i)
#pragma unroll
    for (int j = 0; j < 4; ++j) acc[i][j] = zf;

  const int sr0 = (w*64 + lane) >> 2;
  const int sct = (w*64 + lane) & 3;
#define STAGE_PL(BUF, KT)                                                                 \
  {                                                                                       \
    char* ab_ = (BUF);                                                                    \
    char* bb_ = (BUF) + 16384;                                                            \
    _Pragma("unroll")                                                                     \
    for (int j_ = 0; j_ < 4; ++j_) {        /* A fp32: 4 x 16B per thread */              \
      const int fl_ = j_*256 + w*64 + lane;                                               \
      const int r_  = fl_ >> 3;                                                           \
      const int s_  = fl_ & 7;                                                            \
      const int c_  = s_ ^ (r_ & 7);                                                      \
      gload_lds16(A + (size_t)(m0 + r_)*EE + (KT) + c_*4, ab_ + (j_*4 + w)*1024);         \
    }                                                                                     \
    _Pragma("unroll")                                                                     \
    for (int j_ = 0; j_ < 2; ++j_) {        /* B bf16: 2 x 16B per thread */              \
      const int r_ = sr0 + j_*64;                                                         \
      const int c_ = sct ^ (r_ & 3);                                                      \
      gload_lds16(W + (size_t)(n0 + r_)*EE + (KT) + c_*8, bb_ + j_*4096 + w*1024);        \
    }                                                                                     \
  }

  char* buf0 = smem;
  char* buf1 = smem + 24576;

  STAGE_PL(buf0, 0);
  __syncthreads();

  int cur = 0;
  for (int kt = 0; kt < EE; kt += 32) {
    char* cb = cur ? buf1 : buf0;
    char* nb = cur ? buf0 : buf1;
    if (kt + 32 < EE) STAGE_PL(nb, kt + 32);

    const char* As = cb;           // fp32 [128][128B]
    const char* Bs = cb + 16384;   // bf16 [128][64B]
    v8bf afr[4], bfr[4];
#pragma unroll
    for (int i = 0; i < 4; ++i) {
      const int ra = wm*64 + i*16 + l15;
      const int c0 = (2*lg) ^ (ra & 7);
      const int c1 = (2*lg + 1) ^ (ra & 7);
      v4f f0 = *(const v4f*)(As + ra*128 + c0*16);
      v4f f1 = *(const v4f*)(As + ra*128 + c1*16);
      v8bf a;
      a[0]=(__bf16)f0[0]; a[1]=(__bf16)f0[1]; a[2]=(__bf16)f0[2]; a[3]=(__bf16)f0[3];
      a[4]=(__bf16)f1[0]; a[5]=(__bf16)f1[1]; a[6]=(__bf16)f1[2]; a[7]=(__bf16)f1[3];
      afr[i] = a;
      const int rb = wn*64 + i*16 + l15;
      bfr[i] = *(const v8bf*)(Bs + rb*64 + ((16*lg) ^ ((rb & 3) << 4)));
    }
#pragma unroll
    for (int i = 0; i < 4; ++i)
#pragma unroll
      for (int j = 0; j < 4; ++j)
        acc[i][j] = mfma16(afr[i], bfr[j], acc[i][j]);
    __syncthreads();
    cur ^= 1;
  }
#undef STAGE_PL

  const int nbase = n0 + wn*64;          // 64-aligned => one head
  const int h = nbase >> 6;
  float bsv[4], gmv[4], btv[4];
#pragma unroll
  for (int j = 0; j < 4; ++j) {
    const int d = j*16 + l15;
    bsv[j] = bias[nbase + d];
    gmv[j] = gam[d];
    btv[j] = bet[d];
  }
#pragma unroll
  for (int i = 0; i < 4; ++i)
#pragma unroll
    for (int rr = 0; rr < 4; ++rr) {
      const int row = m0 + wm*64 + i*16 + 4*lg + rr;
      const float mv = maskF[mat*MM + row];
      float x[4];
      float s = 0.f, s2 = 0.f;
#pragma unroll
      for (int j = 0; j < 4; ++j) {
        x[j] = (acc[i][j][rr] + bsv[j]) * mv;
        s += x[j]; s2 += x[j]*x[j];
      }
      s  += __shfl_xor(s, 1, 64);  s  += __shfl_xor(s, 2, 64);
      s  += __shfl_xor(s, 4, 64);  s  += __shfl_xor(s, 8, 64);
      s2 += __shfl_xor(s2, 1, 64); s2 += __shfl_xor(s2, 2, 64);
      s2 += __shfl_xor(s2, 4, 64); s2 += __shfl_xor(s2, 8, 64);
      const float mu  = s * (1.0f/64.0f);
      const float var = s2 * (1.0f/64.0f) - mu*mu;
      const float rstd = rsqrtf(var + LN_EPS);
      const int bidx = row >> 11, sI = row & 2047;
      if (mat == 2) {
        const size_t vbase = 2*BHSD + (((size_t)bidx*HH + h)*DD)*SS;
#pragma unroll
        for (int j = 0; j < 4; ++j)
          Xh[vbase + (size_t)(j*16 + l15)*SS + sI] = (__bf16)((x[j] - mu)*rstd*gmv[j] + btv[j]);
      } else {
        const size_t base = (size_t)mat*BHSD + (((size_t)bidx*HH + h)*SS + sI)*DD;
#pragma unroll
        for (int j = 0; j < 4; ++j)
          Xh[base + j*16 + l15] = (__bf16)((x[j] - mu)*rstd*gmv[j] + btv[j]);
      }
    }
}

// ================= flash attention: r21 + V-fragment hoist (LDS-read diet) =========
// CHANGE vs r21: the 8 V-fragment ds_read_b128s depended only on (g2,df,lg,l15) but
// sat inside the m-loop -> each was read TWICE (VGPR=72 proves no compiler CSE).
// Hoisted to vf[2][4] before the m-loop: LDS reads/wave/iter 24 -> 16 (-33%).
__global__ __launch_bounds__(512) void attn_kernel(const __bf16* Xh, const float* maskF, __bf16* AO) {
  const int bid = blockIdx.x;
  const int xcd = bid & 7;
  const int slot = bid >> 3;
  const int qb = slot & 15;
  const int g = xcd + 8*(slot >> 4);
  const int b = g >> 3, h = g & 7;

  const int t = threadIdx.x;
  const int w = t >> 6, lane = t & 63;
  const int hh = w >> 2, wq = w & 3;        // key-half, q-group
  const int l15 = lane & 15, lg = lane >> 4;

  __shared__ char smem[65536];              // [half][buf]{K 8KB, V 8KB} + overlay

  const size_t headoff = (((size_t)b*HH + h)*SS)*DD;
  const __bf16* Qg = Xh + headoff;
  const __bf16* Kg = Xh + BHSD + headoff;
  const __bf16* Vt = Xh + 2*BHSD + (((size_t)b*HH + h)*DD)*SS;   // [D][S]
  const float* qmF = maskF + (size_t)b*SS;
  const float* kmF = maskF + MM + (size_t)b*SS;

  const int q0 = qb*128 + wq*32;

  // Q fragments, pre-scaled by log2(e)/181 (exp2 domain)
  v8bf qf[2][2];
#pragma unroll
  for (int m = 0; m < 2; ++m)
#pragma unroll
    for (int kd = 0; kd < 2; ++kd) {
      v8bf r = *(const v8bf*)(Qg + (size_t)(q0 + m*16 + l15)*DD + kd*32 + lg*8);
      v8bf o;
#pragma unroll
      for (int e = 0; e < 8; ++e) o[e] = (__bf16)((float)r[e] * (SCALE_INV * LOG2E));
      qf[m][kd] = o;
    }

  v8bf onesb;
#pragma unroll
  for (int e = 0; e < 8; ++e) onesb[e] = (__bf16)1.0f;

  v4f O[2][4];
  v4f lacc[2];
  const v4f zf = {0.f,0.f,0.f,0.f};
#pragma unroll
  for (int m = 0; m < 2; ++m) {
    lacc[m] = zf;
#pragma unroll
    for (int df = 0; df < 4; ++df) O[m][df] = zf;
  }

  const int srow = lane >> 3;
  const int sc   = lane & 7;
  // K source row permutation: LDS row r <- global key sig(r).
#define SIGMA(r) (((r) & ~31) | ((((r)>>2)&3)<<3) | ((((r)>>4)&1)<<2) | ((r)&3))
#define STAGE1(BUFC, KT0)                                                                  \
  {                                                                                        \
    char* kb_ = (BUFC);                                                                    \
    char* vb_ = (BUFC) + 8192;                                                             \
    _Pragma("unroll")                                                                      \
    for (int j_ = 0; j_ < 2; ++j_) {                                                       \
      const int r0_ = wq*16 + j_*8;                                                        \
      const int r_  = r0_ + srow;                                                          \
      const int sg_ = SIGMA(r_);                                                           \
      gload_lds16(Kg + (size_t)((KT0) + sg_)*DD + ((sc ^ (r_ & 7))*8), kb_ + r0_*128);     \
      gload_lds16(Vt + (size_t)r_*SS + (KT0) + ((sc ^ (r_ & 7))*8),  vb_ + r0_*128);       \
    }                                                                                      \
  }

  char* bufA = smem + hh*32768;
  char* bufB = bufA + 16384;

  STAGE1(bufA, hh*64);
  __syncthreads();

  for (int tt = 0; tt < 16; ++tt) {
    char* cur = (tt & 1) ? bufB : bufA;
    char* nxt = (tt & 1) ? bufA : bufB;
    if (tt + 1 < 16) STAGE1(nxt, ((tt+1)*2 + hh)*64);   // hides under compute(cur)

    const int kt0 = (tt*2 + hh)*64;
    char* kb = cur;
    char* vb = cur + 8192;

    // ---- K fragments from LDS (swizzled read; rows hold sig-permuted keys) ----
    v8bf kf[4][2];
#pragma unroll
    for (int f = 0; f < 4; ++f)
#pragma unroll
      for (int kd = 0; kd < 2; ++kd) {
        const int rr = f*16 + l15;
        kf[f][kd] = *(const v8bf*)(kb + rr*128 + (((kd*4 + lg) ^ (rr & 7))*16));
      }

    // ---- V fragments from LDS, HOISTED (independent of m) ----
    v8bf vf[2][4];
#pragma unroll
    for (int g2 = 0; g2 < 2; ++g2)
#pragma unroll
      for (int df = 0; df < 4; ++df) {
        const int rv = df*16 + l15;
        vf[g2][df] = *(const v8bf*)(vb + rv*128 + (((g2*4 + lg) ^ (rv & 7))*16));
      }

    // ---- S^T = K Q^T : lane q=l15; (f,rr) -> global key kt0+sig(f*16+4lg+rr) ----
    v4f st[2][4];
#pragma unroll
    for (int m = 0; m < 2; ++m)
#pragma unroll
      for (int f = 0; f < 4; ++f) st[m][f] = zf;
#pragma unroll
    for (int kd = 0; kd < 2; ++kd)
#pragma unroll
      for (int f = 0; f < 4; ++f)
#pragma unroll
        for (int m = 0; m < 2; ++m)
          st[m][f] = mfma16(kf[f][kd], qf[m][kd], st[m][f]);

    // key-mask for permuted keys: (f,rr) -> (f>>1)*32 + (f&1)*4 + 8*lg + rr (contig in rr)
    v4f km4[4];
#pragma unroll
    for (int f = 0; f < 4; ++f)
      km4[f] = *(const v4f*)(kmF + kt0 + (f >> 1)*32 + (f & 1)*4 + 8*lg);

    // ---- fixed-max softmax (native exp2) + PV at K=32 + MFMA row-sum ----
#pragma unroll
    for (int m = 0; m < 2; ++m) {
      float p[4][4];
#pragma unroll
      for (int f = 0; f < 4; ++f)
#pragma unroll
        for (int rr = 0; rr < 4; ++rr)
          p[f][rr] = fexp2(st[m][f][rr]) * km4[f][rr];
#pragma unroll
      for (int g2 = 0; g2 < 2; ++g2) {
        v8bf pa;
        pa[0] = (__bf16)p[2*g2][0];   pa[1] = (__bf16)p[2*g2][1];
        pa[2] = (__bf16)p[2*g2][2];   pa[3] = (__bf16)p[2*g2][3];
        pa[4] = (__bf16)p[2*g2+1][0]; pa[5] = (__bf16)p[2*g2+1][1];
        pa[6] = (__bf16)p[2*g2+1][2]; pa[7] = (__bf16)p[2*g2+1][3];
        lacc[m] = mfma16(pa, onesb, lacc[m]);      // rowsum: D[q][*] = sum_k p
#pragma unroll
        for (int df = 0; df < 4; ++df)
          O[m][df] = mfma16(pa, vf[g2][df], O[m][df]);
      }
    }
    __syncthreads();   // drains stage(next); protects cur overwrite at tt+2
  }
#undef STAGE1
#undef SIGMA

  // ---- combine halves in LDS (loop ended with barrier) ----
  // lacc layout == O layout: lane holds q = 4*lg+rr (all l15 columns identical).
  float (*Pp)[32][65] = (float (*)[32][65])smem;            // [4][32][65] = 33,280 B
  float (*Lp)[32]     = (float (*)[32])(smem + 4*32*65*4);  // +512 B
  if (hh == 1) {
#pragma unroll
    for (int m = 0; m < 2; ++m)
#pragma unroll
      for (int df = 0; df < 4; ++df)
#pragma unroll
        for (int rr = 0; rr < 4; ++rr)
          Pp[wq][m*16 + 4*lg + rr][df*16 + l15] = O[m][df][rr];
    if (l15 == 0) {
#pragma unroll
      for (int m = 0; m < 2; ++m)
#pragma unroll
        for (int rr = 0; rr < 4; ++rr)
          Lp[wq][m*16 + 4*lg + rr] = lacc[m][rr];
    }
  }
  __syncthreads();
  if (hh == 0) {
#pragma unroll
    for (int m = 0; m < 2; ++m)
#pragma unroll
      for (int df = 0; df < 4; ++df)
#pragma unroll
        for (int rr = 0; rr < 4; ++rr)
          O[m][df][rr] += Pp[wq][m*16 + 4*lg + rr][df*16 + l15];
#pragma unroll
    for (int m = 0; m < 2; ++m)
#pragma unroll
      for (int rr = 0; rr < 4; ++rr) {
        const float lr = lacc[m][rr] + Lp[wq][m*16 + 4*lg + rr];
        const int qrow = q0 + m*16 + 4*lg + rr;
        const float scl = qmF[qrow] / fmaxf(lr, 1e-30f);
#pragma unroll
        for (int df = 0; df < 4; ++df)
          AO[(size_t)(b*SS + qrow)*EE + h*DD + df*16 + l15] = (__bf16)(O[m][df][rr] * scl);
      }
  }
}

// ================= output GEMM: out = (AO @ Wo^T + bo) * qmask =================
// (unchanged from round 11)
__global__ __launch_bounds__(256) void gemm_out(const __bf16* AO, const __bf16* Wb,
                                                const float* bo, const float* maskF, float* out) {
  const int m0 = blockIdx.x * 128;
  const int n0 = blockIdx.y * 128;
  const __bf16* A = AO;
  const __bf16* W = Wb + (size_t)3*EE*EE;   // Wo

  __shared__ char smem[32768];

  const int t = threadIdx.x;
  const int lane = t & 63, w = t >> 6;
  const int wm = w >> 1, wn = w & 1;
  const int l15 = lane & 15, lg = lane >> 4;

  v4f acc[4][4];
  const v4f zf = {0.f,0.f,0.f,0.f};
#pragma unroll
  for (int i = 0; i < 4; ++i)
#pragma unroll
    for (int j = 0; j < 4; ++j) acc[i][j] = zf;

  const int sr0 = (w*64 + lane) >> 2;
  const int sct = (w*64 + lane) & 3;
#define STAGE_PL(BUF, KT)                                                                 \
  {                                                                                       \
    char* ab_ = (BUF);                                                                    \
    char* bb_ = (BUF) + 8192;                                                             \
    _Pragma("unroll")                                                                     \
    for (int j_ = 0; j_ < 2; ++j_) {                                                      \
      const int r_ = sr0 + j_*64;                                                         \
      const int c_ = sct ^ (r_ & 3);                                                      \
      gload_lds16(A + (size_t)(m0 + r_)*EE + (KT) + c_*8, ab_ + j_*4096 + w*1024);        \
      gload_lds16(W + (size_t)(n0 + r_)*EE + (KT) + c_*8, bb_ + j_*4096 + w*1024);        \
    }                                                                                     \
  }

  char* buf0 = smem;
  char* buf1 = smem + 16384;

  STAGE_PL(buf0, 0);
  __syncthreads();

  int cur = 0;
  for (int kt = 0; kt < EE; kt += 32) {
    char* cb = cur ? buf1 : buf0;
    char* nb = cur ? buf0 : buf1;
    if (kt + 32 < EE) STAGE_PL(nb, kt + 32);

    const char* As = cb;
    const char* Bs = cb + 8192;
    v8bf afr[4], bfr[4];
#pragma unroll
    for (int i = 0; i < 4; ++i) {
      const int ra = wm*64 + i*16 + l15;
      afr[i] = *(const v8bf*)(As + ra*64 + ((16*lg) ^ ((ra & 3) << 4)));
      const int rb = wn*64 + i*16 + l15;
      bfr[i] = *(const v8bf*)(Bs + rb*64 + ((16*lg) ^ ((rb & 3) << 4)));
    }
#pragma unroll
    for (int i = 0; i < 4; ++i)
#pragma unroll
      for (int j = 0; j < 4; ++j)
        acc[i][j] = mfma16(afr[i], bfr[j], acc[i][j]);
    __syncthreads();
    cur ^= 1;
  }
#undef STAGE_PL

  float bsv[4]; int ncol[4];
#pragma unroll
  for (int j = 0; j < 4; ++j) {
    ncol[j] = n0 + wn*64 + j*16 + l15;
    bsv[j] = bo[ncol[j]];
  }
#pragma unroll
  for (int i = 0; i < 4; ++i)
#pragma unroll
    for (int rr = 0; rr < 4; ++rr) {
      const int row = m0 + wm*64 + i*16 + 4*lg + rr;
      const float mv = maskF[row];   // query mask
#pragma unroll
      for (int j = 0; j < 4; ++j)
        out[(size_t)row*EE + ncol[j]] = (acc[i][j][rr] + bsv[j]) * mv;
    }
}

// ================= launcher =================
extern "C" void kernel_launch(void* const* d_in, const int* in_sizes, int n_in,
                              void* d_out, int out_size, void* d_ws, size_t ws_size,
                              hipStream_t stream) {
  const float* q  = (const float*)d_in[0];
  const float* k  = (const float*)d_in[1];
  const float* v  = (const float*)d_in[2];
  const float* Wq = (const float*)d_in[3];
  const float* bq = (const float*)d_in[4];
  const float* Wk = (const float*)d_in[5];
  const float* bk = (const float*)d_in[6];
  const float* Wv = (const float*)d_in[7];
  const float* bv = (const float*)d_in[8];
  const float* Wo = (const float*)d_in[9];
  const float* bo = (const float*)d_in[10];
  const float* gq = (const float*)d_in[11];
  const float* betaq = (const float*)d_in[12];
  const float* gk = (const float*)d_in[13];
  const float* betak = (const float*)d_in[14];
  const float* gv = (const float*)d_in[15];
  const float* betav = (const float*)d_in[16];

  char* ws = (char*)d_ws;
  __bf16* Wb = (__bf16*)(ws + oWb);
  __bf16* Xh = (__bf16*)(ws + oXh);
  __bf16* AO = (__bf16*)(ws + oAO);
  float*  maskF = (float*)(ws + oMk);

  mask_kernel<<<dim3(96), dim3(256), 0, stream>>>(d_in[17], d_in[18], d_in[19], maskF);
  convert_kernel<<<dim3(1024), dim3(256), 0, stream>>>(Wq, Wk, Wv, Wo, Wb);
  gemm_proj_ln<<<dim3(64, 4, 3), dim3(256), 0, stream>>>(q, k, v, Wb, bq, bk, bv,
                                                         gq, betaq, gk, betak, gv, betav,
                                                         maskF, Xh);
  attn_kernel<<<dim3(512), dim3(512), 0, stream>>>(Xh, maskF, AO);
  gemm_out<<<dim3(64, 4, 1), dim3(256), 0, stream>>>(AO, Wb, bo, maskF, (float*)d_out);
}